// Round 5
// baseline (551.496 us; speedup 1.0000x reference)
//
#include <hip/hip_runtime.h>

#define NE 50000
#define NN 10000
#define KH 96
#define KE 128          // padded K: 96 + bias row (=1*b2) + zeros
#define WN 6928
#define WP 7744         // permuted+padded W2 column count = 484 tiles of 16
#define IN_SZ 156
#define EPW 32          // edges per workgroup in tp_kernel

typedef __attribute__((ext_vector_type(8))) short short8;
typedef __attribute__((ext_vector_type(4))) float float4v;

__device__ __forceinline__ unsigned short f2bf(float x) {
  unsigned u = __float_as_uint(x);
  unsigned r = (u + 0x7FFFu + ((u >> 16) & 1u)) >> 16;   // RNE
  return (unsigned short)r;
}
__device__ __forceinline__ float b2f(unsigned short u) {
  return __uint_as_float(((unsigned)u) << 16);
}

// ---------------- Kernel C: cast edge_attr -> bf16 rows; W1 -> bf16 transposed ----------------
__global__ __launch_bounds__(256) void cast_kernel(
    const float* __restrict__ edge_attr, const float* __restrict__ W1,
    unsigned short* __restrict__ ea_bf, unsigned short* __restrict__ W1T)
{
  int idx = blockIdx.x * 256 + threadIdx.x;
  const int nea = NE * KH / 8;                  // 600000
  if (idx < nea) {
    const float* p = edge_attr + (size_t)idx * 8;
    float4 x = *(const float4*)p, y = *(const float4*)(p + 4);
    uint4 pk;
    pk.x = f2bf(x.x) | ((unsigned)f2bf(x.y) << 16);
    pk.y = f2bf(x.z) | ((unsigned)f2bf(x.w) << 16);
    pk.z = f2bf(y.x) | ((unsigned)f2bf(y.y) << 16);
    pk.w = f2bf(y.z) | ((unsigned)f2bf(y.w) << 16);
    *(uint4*)(ea_bf + (size_t)idx * 8) = pk;
  } else {
    int j = idx - nea;
    if (j < KH * KH) {
      int c = j / KH, k = j - c * KH;
      W1T[c * KH + k] = f2bf(W1[k * KH + c]);   // W1T[col][k]
    }
  }
}

// ---------------- Kernel 1: h_ext via MFMA: relu(ea @ W1 + b1), pad cols 96..127 ----------------
// 384 threads = 6 waves; wave w = col tile w (16 cols); wg = 16 edges.
__global__ __launch_bounds__(384) void mlp1_kernel(
    const unsigned short* __restrict__ ea_bf, const unsigned short* __restrict__ W1T,
    const float* __restrict__ b1, unsigned short* __restrict__ h_ext)
{
  const int tid = threadIdx.x;
  const int e0 = blockIdx.x * 16;
  const int w = tid >> 6, l = tid & 15, q = (tid >> 4) & 3;

  short8 a[3], b[3];
  #pragma unroll
  for (int s = 0; s < 3; ++s) {
    a[s] = *(const short8*)(ea_bf + (size_t)(e0 + l) * KH + s * 32 + q * 8);
    b[s] = *(const short8*)(W1T + (size_t)(w * 16 + l) * KH + s * 32 + q * 8);
  }
  float4v C = {0.f, 0.f, 0.f, 0.f};
  #pragma unroll
  for (int s = 0; s < 3; ++s)
    C = __builtin_amdgcn_mfma_f32_16x16x32_bf16(a[s], b[s], C, 0, 0, 0);

  float bv = b1[w * 16 + l];
  #pragma unroll
  for (int r = 0; r < 4; ++r)
    h_ext[(size_t)(e0 + q * 4 + r) * KE + w * 16 + l] = f2bf(fmaxf(C[r] + bv, 0.f));

  for (int idx = tid; idx < 16 * 32; idx += 384) {   // pad cols 96..127
    int e = idx >> 5, c = 96 + (idx & 31);
    h_ext[(size_t)(e0 + e) * KE + c] = (c == 96) ? (unsigned short)0x3F80 : (unsigned short)0;
  }
}

// ---------------- Kernel P: permuted W2P[np][k] bf16 ----------------
__global__ __launch_bounds__(256) void w2p_kernel(
    const float* __restrict__ W2, const float* __restrict__ b2,
    unsigned short* __restrict__ W2P)
{
  int idx = blockIdx.x * 256 + threadIdx.x;
  if (idx >= WP * 16) return;
  int np = idx >> 4, ch = idx & 15, k0 = ch * 8;
  int c;
  if (np < 2784) c = np;
  else if (np < 3872) { int rel = np - 2784, i = rel >> 4, o = rel & 15; c = (o < 10) ? 2784 + i * 10 + o : -1; }
  else if (np < 4960) { int rel = np - 3872, i = rel >> 4, o = rel & 15; c = (o < 10) ? 3464 + i * 10 + o : -1; }
  else c = 4144 + (np - 4960);

  unsigned short o8[8];
  #pragma unroll
  for (int j = 0; j < 8; ++j) {
    int k = k0 + j;
    float v = 0.f;
    if (c >= 0) v = (k < KH) ? W2[(size_t)k * WN + c] : (k == KH ? b2[c] : 0.f);
    o8[j] = f2bf(v);
  }
  uint4 pk;
  pk.x = o8[0] | ((unsigned)o8[1] << 16);
  pk.y = o8[2] | ((unsigned)o8[3] << 16);
  pk.z = o8[4] | ((unsigned)o8[5] << 16);
  pk.w = o8[6] | ((unsigned)o8[7] << 16);
  *(uint4*)(W2P + (size_t)np * KE + k0) = pk;
}

// ---------------- Kernel 2: MFMA w-GEMM fused with TP; depth-2 B prefetch ----------------
__global__ __launch_bounds__(512, 4) void tp_kernel(
    const unsigned short* __restrict__ h_ext, const float* __restrict__ node_attr,
    const int* __restrict__ edge_index, const float* __restrict__ edge_sh,
    const unsigned short* __restrict__ W2P,
    float* __restrict__ acc, int* __restrict__ icnt)
{
  __shared__ float sInl[EPW][165];                 // union: input stage, then sOut[e][156]
  __shared__ float sF0[2][58][EPW];                // scalar feats [fam][i][e]
  __shared__ unsigned short sF1[2][68][3][EPW];    // vector feats bf16 [fam][i][cc][e]
  __shared__ float sShs[EPW][4];
  __shared__ int sSrc[EPW], sDst[EPW];

  const int tid = threadIdx.x;
  const int e0 = blockIdx.x * EPW;

  if (tid < EPW) {
    int ok = (e0 + tid) < NE;
    int s = ok ? edge_index[e0 + tid] : 0;
    int d = ok ? edge_index[NE + e0 + tid] : 0;
    sSrc[tid] = s; sDst[tid] = d;
    if (ok) atomicAdd(&icnt[s], 1);
  }
  if (tid >= 128 && tid < 128 + EPW * 4) {
    int t2 = tid - 128;
    int e = t2 >> 2, c = t2 & 3;
    sShs[e][c] = ((e0 + e) < NE) ? edge_sh[(size_t)(e0 + e) * 4 + c] : 0.f;
  }
  __syncthreads();

  for (int idx = tid; idx < EPW * IN_SZ; idx += 512) {
    int e = idx / IN_SZ, f = idx - e * IN_SZ;
    sInl[e][f] = node_attr[(size_t)sDst[e] * IN_SZ + f];
  }
  __syncthreads();

  { // ---- feature construction: 16 workers per edge ----
    const int e = tid >> 4, j = tid & 15;
    const float sh0 = sShs[e][0], sx = sShs[e][1], sy = sShs[e][2], sz = sShs[e][3];
    const float i3 = 0.57735026918962576f, i2 = 0.70710678118654752f;
    for (int i = j; i < 48; i += 16) {
      float v0 = sInl[e][i], w0 = sInl[e][108 + i];
      sF0[0][i][e] = v0 * sh0;
      sF0[1][10 + i][e] = w0 * sh0;
      sF1[0][i][0][e] = f2bf(v0 * sx); sF1[0][i][1][e] = f2bf(v0 * sy); sF1[0][i][2][e] = f2bf(v0 * sz);
      sF1[1][20 + i][0][e] = f2bf(w0 * sx); sF1[1][20 + i][1][e] = f2bf(w0 * sy); sF1[1][20 + i][2][e] = f2bf(w0 * sz);
    }
    if (j < 10) {
      const int v = j;
      float ax = sInl[e][48 + 3 * v], ay = sInl[e][48 + 3 * v + 1], az = sInl[e][48 + 3 * v + 2];
      float bx = sInl[e][78 + 3 * v], by = sInl[e][78 + 3 * v + 1], bz = sInl[e][78 + 3 * v + 2];
      sF0[0][48 + v][e] = (ax * sx + ay * sy + az * sz) * i3;
      sF0[1][v][e]      = (bx * sx + by * sy + bz * sz) * i3;
      sF1[0][48 + v][0][e] = f2bf(ax * sh0); sF1[0][48 + v][1][e] = f2bf(ay * sh0); sF1[0][48 + v][2][e] = f2bf(az * sh0);
      sF1[0][58 + v][0][e] = f2bf((by * sz - bz * sy) * i2);
      sF1[0][58 + v][1][e] = f2bf((bz * sx - bx * sz) * i2);
      sF1[0][58 + v][2][e] = f2bf((bx * sy - by * sx) * i2);
      sF1[1][v][0][e] = f2bf((ay * sz - az * sy) * i2);
      sF1[1][v][1][e] = f2bf((az * sx - ax * sz) * i2);
      sF1[1][v][2][e] = f2bf((ax * sy - ay * sx) * i2);
      sF1[1][10 + v][0][e] = f2bf(bx * sh0); sF1[1][10 + v][1][e] = f2bf(by * sh0); sF1[1][10 + v][2][e] = f2bf(bz * sh0);
    }
  }
  __syncthreads();
  // sInl now becomes sOut: every element [e][0..155] written exactly once below.

  const int wv = tid >> 6;            // 0..7 = column group
  const int l = tid & 15, q = (tid >> 4) & 3;

  short8 Af[2][4];
  #pragma unroll
  for (int m = 0; m < 2; ++m) {
    size_t erow = (size_t)(e0 + m * 16 + l) * KE;
    #pragma unroll
    for (int s = 0; s < 4; ++s)
      Af[m][s] = *(const short8*)(h_ext + erow + s * 32 + q * 8);
  }

  int fam4, ob = 0, tbase, tstride;
  if (wv < 3)      { fam4 = 0; ob = wv;     tbase = wv;           tstride = 3; }
  else if (wv == 3){ fam4 = 1;              tbase = 174;          tstride = 1; }
  else if (wv == 4){ fam4 = 2;              tbase = 242;          tstride = 1; }
  else             { fam4 = 3; ob = wv - 5; tbase = 310 + wv - 5; tstride = 3; }

  // depth-2 prefetch pipeline
  short8 B0[4], B1[4];
  {
    size_t r0_ = (size_t)(tbase * 16 + l) * KE;
    size_t r1_ = (size_t)((tbase + tstride) * 16 + l) * KE;
    #pragma unroll
    for (int s = 0; s < 4; ++s) {
      B0[s] = *(const short8*)(W2P + r0_ + s * 32 + q * 8);
      B1[s] = *(const short8*)(W2P + r1_ + s * 32 + q * 8);
    }
  }
  int tld = tbase + 2 * tstride;

  if (fam4 == 0 || fam4 == 3) {
    // ---------------- scalar families ----------------
    const int sf = (fam4 == 0) ? 0 : 1;
    float r0[4] = {0.f, 0.f, 0.f, 0.f}, r1[4] = {0.f, 0.f, 0.f, 0.f};
    #pragma unroll 2
    for (int i = 0; i < 58; ++i) {
      short8 B2[4];
      {
        int tn = (i + 2 < 58) ? tld : tbase;
        size_t brow = (size_t)(tn * 16 + l) * KE;
        #pragma unroll
        for (int s = 0; s < 4; ++s) B2[s] = *(const short8*)(W2P + brow + s * 32 + q * 8);
      }
      float4 f0 = *(const float4*)&sF0[sf][i][q * 4];
      float4 f1 = *(const float4*)&sF0[sf][i][16 + q * 4];
      float4v C0 = {0.f, 0.f, 0.f, 0.f}, C1 = {0.f, 0.f, 0.f, 0.f};
      #pragma unroll
      for (int s = 0; s < 4; ++s) {
        C0 = __builtin_amdgcn_mfma_f32_16x16x32_bf16(Af[0][s], B0[s], C0, 0, 0, 0);
        C1 = __builtin_amdgcn_mfma_f32_16x16x32_bf16(Af[1][s], B0[s], C1, 0, 0, 0);
      }
      r0[0] += C0[0] * f0.x; r0[1] += C0[1] * f0.y; r0[2] += C0[2] * f0.z; r0[3] += C0[3] * f0.w;
      r1[0] += C1[0] * f1.x; r1[1] += C1[1] * f1.y; r1[2] += C1[2] * f1.z; r1[3] += C1[3] * f1.w;
      #pragma unroll
      for (int s = 0; s < 4; ++s) { B0[s] = B1[s]; B1[s] = B2[s]; }
      tld += tstride;
    }
    const int col = ((fam4 == 0) ? 0 : 108) + ob * 16 + l;
    #pragma unroll
    for (int r = 0; r < 4; ++r) {
      sInl[q * 4 + r][col]      = r0[r];
      sInl[16 + q * 4 + r][col] = r1[r];
    }
  } else {
    // ---------------- vector families ----------------
    const int vf = fam4 - 1;
    float r0[4][3] = {{0.f}}, r1[4][3] = {{0.f}};
    #pragma unroll 2
    for (int i = 0; i < 68; ++i) {
      short8 B2[4];
      {
        int tn = (i + 2 < 68) ? tld : tbase;
        size_t brow = (size_t)(tn * 16 + l) * KE;
        #pragma unroll
        for (int s = 0; s < 4; ++s) B2[s] = *(const short8*)(W2P + brow + s * 32 + q * 8);
      }
      ushort4 g0[3], g1[3];
      #pragma unroll
      for (int cc = 0; cc < 3; ++cc) {
        g0[cc] = *(const ushort4*)&sF1[vf][i][cc][q * 4];
        g1[cc] = *(const ushort4*)&sF1[vf][i][cc][16 + q * 4];
      }
      float4v C0 = {0.f, 0.f, 0.f, 0.f}, C1 = {0.f, 0.f, 0.f, 0.f};
      #pragma unroll
      for (int s = 0; s < 4; ++s) {
        C0 = __builtin_amdgcn_mfma_f32_16x16x32_bf16(Af[0][s], B0[s], C0, 0, 0, 0);
        C1 = __builtin_amdgcn_mfma_f32_16x16x32_bf16(Af[1][s], B0[s], C1, 0, 0, 0);
      }
      #pragma unroll
      for (int cc = 0; cc < 3; ++cc) {
        r0[0][cc] += C0[0] * b2f(g0[cc].x); r0[1][cc] += C0[1] * b2f(g0[cc].y);
        r0[2][cc] += C0[2] * b2f(g0[cc].z); r0[3][cc] += C0[3] * b2f(g0[cc].w);
        r1[0][cc] += C1[0] * b2f(g1[cc].x); r1[1][cc] += C1[1] * b2f(g1[cc].y);
        r1[2][cc] += C1[2] * b2f(g1[cc].z); r1[3][cc] += C1[3] * b2f(g1[cc].w);
      }
      #pragma unroll
      for (int s = 0; s < 4; ++s) { B0[s] = B1[s]; B1[s] = B2[s]; }
      tld += 1;
    }
    if (l < 10) {
      const int col = ((vf == 0) ? 48 : 78) + 3 * l;
      #pragma unroll
      for (int r = 0; r < 4; ++r)
        #pragma unroll
        for (int cc = 0; cc < 3; ++cc) {
          sInl[q * 4 + r][col + cc]      = r0[r][cc];
          sInl[16 + q * 4 + r][col + cc] = r1[r][cc];
        }
    }
  }
  __syncthreads();

  // ---- scatter to global ----
  const float n58 = 0.13130643285972254f, n68 = 0.12126781251816650f;
  for (int idx = tid; idx < EPW * IN_SZ; idx += 512) {
    int e = idx / IN_SZ, o = idx - e * IN_SZ;
    if (e0 + e < NE) {
      float nrm = (o < 48 || o >= 108) ? n58 : n68;
      unsafeAtomicAdd(&acc[(size_t)sSrc[e] * IN_SZ + o], sInl[e][o] * nrm);
    }
  }
}

// ---------------- Kernel 3: out = acc / max(cnt,1) + node_attr ----------------
__global__ __launch_bounds__(256) void finalize_kernel(
    const float* __restrict__ acc, const int* __restrict__ icnt,
    const float* __restrict__ node_attr, float* __restrict__ out)
{
  int idx = blockIdx.x * 256 + threadIdx.x;
  if (idx < NN * IN_SZ) {
    int n = idx / IN_SZ;
    out[idx] = acc[idx] / fmaxf((float)icnt[n], 1.f) + node_attr[idx];
  }
}

extern "C" void kernel_launch(void* const* d_in, const int* in_sizes, int n_in,
                              void* d_out, int out_size, void* d_ws, size_t ws_size,
                              hipStream_t stream)
{
  const float* node_attr  = (const float*)d_in[0];
  const int*   edge_index = (const int*)d_in[1];
  const float* edge_attr  = (const float*)d_in[2];
  const float* edge_sh    = (const float*)d_in[3];
  const float* W1 = (const float*)d_in[4];
  const float* b1 = (const float*)d_in[5];
  const float* W2 = (const float*)d_in[6];
  const float* b2 = (const float*)d_in[7];
  float* out = (float*)d_out;

  unsigned short* h_ext = (unsigned short*)d_ws;              // 50016 * 128 bf16
  unsigned short* W2P   = h_ext + (size_t)50016 * KE;         // 7744 * 128 bf16
  unsigned short* ea_bf = W2P + (size_t)WP * KE;              // 50000 * 96 bf16 (dead after mlp1)
  unsigned short* W1T   = ea_bf + (size_t)NE * KH;            // 96*96 bf16
  float* acc  = (float*)ea_bf;                                // ALIAS: reused after mlp1
  int*   icnt = (int*)(W1T + KH * KH + 64);                   // 10000 i32 (past W1T)

  // order matters: cast+mlp1 consume ea_bf, THEN acc (same memory) is zeroed.
  cast_kernel<<<(NE * KH / 8 + KH * KH + 255) / 256, 256, 0, stream>>>(edge_attr, W1, ea_bf, W1T);
  w2p_kernel<<<(WP * 16) / 256, 256, 0, stream>>>(W2, b2, W2P);
  mlp1_kernel<<<NE / 16, 384, 0, stream>>>(ea_bf, W1T, b1, h_ext);
  hipMemsetAsync(acc, 0, (size_t)NN * IN_SZ * sizeof(float), stream);
  hipMemsetAsync(icnt, 0, (size_t)NN * sizeof(int), stream);
  hipMemsetAsync(h_ext + (size_t)50000 * KE, 0, (size_t)16 * KE * sizeof(unsigned short), stream);
  tp_kernel<<<(NE + EPW - 1) / EPW, 512, 0, stream>>>(h_ext, node_attr, edge_index,
                                                      edge_sh, W2P, acc, icnt);
  finalize_kernel<<<(NN * IN_SZ + 255) / 256, 256, 0, stream>>>(acc, icnt, node_attr, out);
}

// Round 6
// 534.094 us; speedup vs baseline: 1.0326x; 1.0326x over previous
//
#include <hip/hip_runtime.h>

#define NE 50000
#define NN 10000
#define KH 96
#define KE 128          // padded K: 96 + bias row (=1*b2) + zeros
#define WN 6928
#define WP 7744         // permuted+padded W2 column count = 484 tiles of 16
#define IN_SZ 156
#define EPW 32          // edges per workgroup in tp_kernel

typedef __attribute__((ext_vector_type(8))) short short8;
typedef __attribute__((ext_vector_type(4))) float float4v;

__device__ __forceinline__ unsigned short f2bf(float x) {
  unsigned u = __float_as_uint(x);
  unsigned r = (u + 0x7FFFu + ((u >> 16) & 1u)) >> 16;   // RNE
  return (unsigned short)r;
}
__device__ __forceinline__ float b2f(unsigned short u) {
  return __uint_as_float(((unsigned)u) << 16);
}

// ---------------- Kernel C: cast edge_attr -> bf16 rows; W1 -> bf16 transposed ----------------
__global__ __launch_bounds__(256) void cast_kernel(
    const float* __restrict__ edge_attr, const float* __restrict__ W1,
    unsigned short* __restrict__ ea_bf, unsigned short* __restrict__ W1T)
{
  int idx = blockIdx.x * 256 + threadIdx.x;
  const int nea = NE * KH / 8;                  // 600000
  if (idx < nea) {
    const float* p = edge_attr + (size_t)idx * 8;
    float4 x = *(const float4*)p, y = *(const float4*)(p + 4);
    uint4 pk;
    pk.x = f2bf(x.x) | ((unsigned)f2bf(x.y) << 16);
    pk.y = f2bf(x.z) | ((unsigned)f2bf(x.w) << 16);
    pk.z = f2bf(y.x) | ((unsigned)f2bf(y.y) << 16);
    pk.w = f2bf(y.z) | ((unsigned)f2bf(y.w) << 16);
    *(uint4*)(ea_bf + (size_t)idx * 8) = pk;
  } else {
    int j = idx - nea;
    if (j < KH * KH) {
      int c = j / KH, k = j - c * KH;
      W1T[c * KH + k] = f2bf(W1[k * KH + c]);   // W1T[col][k]
    }
  }
}

// ---------------- Kernel 1: h_ext via MFMA: relu(ea @ W1 + b1), pad cols 96..127 ----------------
__global__ __launch_bounds__(384) void mlp1_kernel(
    const unsigned short* __restrict__ ea_bf, const unsigned short* __restrict__ W1T,
    const float* __restrict__ b1, unsigned short* __restrict__ h_ext)
{
  const int tid = threadIdx.x;
  const int e0 = blockIdx.x * 16;
  const int w = tid >> 6, l = tid & 15, q = (tid >> 4) & 3;

  short8 a[3], b[3];
  #pragma unroll
  for (int s = 0; s < 3; ++s) {
    a[s] = *(const short8*)(ea_bf + (size_t)(e0 + l) * KH + s * 32 + q * 8);
    b[s] = *(const short8*)(W1T + (size_t)(w * 16 + l) * KH + s * 32 + q * 8);
  }
  float4v C = {0.f, 0.f, 0.f, 0.f};
  #pragma unroll
  for (int s = 0; s < 3; ++s)
    C = __builtin_amdgcn_mfma_f32_16x16x32_bf16(a[s], b[s], C, 0, 0, 0);

  float bv = b1[w * 16 + l];
  #pragma unroll
  for (int r = 0; r < 4; ++r)
    h_ext[(size_t)(e0 + q * 4 + r) * KE + w * 16 + l] = f2bf(fmaxf(C[r] + bv, 0.f));

  for (int idx = tid; idx < 16 * 32; idx += 384) {   // pad cols 96..127
    int e = idx >> 5, c = 96 + (idx & 31);
    h_ext[(size_t)(e0 + e) * KE + c] = (c == 96) ? (unsigned short)0x3F80 : (unsigned short)0;
  }
}

// ---------------- Kernel P: permuted W2P[np][k] bf16; thread = np (coalesced col reads) ------
__global__ __launch_bounds__(256) void w2p_kernel(
    const float* __restrict__ W2, const float* __restrict__ b2,
    unsigned short* __restrict__ W2P)
{
  int np = blockIdx.x * 256 + threadIdx.x;
  if (np >= WP) return;
  int c;
  if (np < 2784) c = np;
  else if (np < 3872) { int rel = np - 2784, i = rel >> 4, o = rel & 15; c = (o < 10) ? 2784 + i * 10 + o : -1; }
  else if (np < 4960) { int rel = np - 3872, i = rel >> 4, o = rel & 15; c = (o < 10) ? 3464 + i * 10 + o : -1; }
  else c = 4144 + (np - 4960);

  unsigned short* dst = W2P + (size_t)np * KE;
  if (c < 0) {
    uint4 z = {0u, 0u, 0u, 0u};
    for (int k0 = 0; k0 < KE; k0 += 8) *(uint4*)(dst + k0) = z;
    return;
  }
  const float* src = W2 + c;
  float bvc = b2[c];
  for (int k0 = 0; k0 < KE; k0 += 8) {
    unsigned short o8[8];
    #pragma unroll
    for (int j = 0; j < 8; ++j) {
      int k = k0 + j;
      float v = (k < KH) ? src[(size_t)k * WN] : (k == KH ? bvc : 0.f);
      o8[j] = f2bf(v);
    }
    uint4 pk;
    pk.x = o8[0] | ((unsigned)o8[1] << 16);
    pk.y = o8[2] | ((unsigned)o8[3] << 16);
    pk.z = o8[4] | ((unsigned)o8[5] << 16);
    pk.w = o8[6] | ((unsigned)o8[7] << 16);
    *(uint4*)(dst + k0) = pk;
  }
}

// ---------------- Kernel 2: MFMA w-GEMM fused with TP ----------------
// 512 threads = 8 waves, balanced:
//   wv 0,1: fam0e (i-half 0/1, 3 ob-phases x 30 iters)   wv 2,3: fam0o (same)
//   wv 4,5: fam1o (i-half, 34/36 iters)                  wv 6,7: fam1e
// Each wave covers all 32 edges (2 MFMA row-halves). Clean 2-buffer pipeline, no copies.
// i-dims padded (58->60, 68->70) with zeroed feature rows; B tile index clamped for pads.
__global__ __launch_bounds__(512, 4) void tp_kernel(
    const unsigned short* __restrict__ h_ext, const float* __restrict__ node_attr,
    const int* __restrict__ edge_index, const float* __restrict__ edge_sh,
    const unsigned short* __restrict__ W2P,
    float* __restrict__ acc, int* __restrict__ icnt)
{
  __shared__ unsigned short sIn[EPW][160];         // bf16 gathered node_attr
  __shared__ float sOut[EPW][160];                 // f32 output staging
  __shared__ unsigned short sF0[2][60][EPW];       // scalar feats bf16 [fam][i][e]
  __shared__ unsigned short sF1[2][70][3][EPW];    // vector feats bf16 [fam][i][cc][e]
  __shared__ float sShs[EPW][4];
  __shared__ int sSrc[EPW], sDst[EPW];

  const int tid = threadIdx.x;
  const int e0 = blockIdx.x * EPW;

  if (tid < EPW) {
    int ok = (e0 + tid) < NE;
    int s = ok ? edge_index[e0 + tid] : 0;
    int d = ok ? edge_index[NE + e0 + tid] : 0;
    sSrc[tid] = s; sDst[tid] = d;
    if (ok) atomicAdd(&icnt[s], 1);
  }
  if (tid >= 128 && tid < 256) {
    int t2 = tid - 128;
    int e = t2 >> 2, c = t2 & 3;
    sShs[e][c] = ((e0 + e) < NE) ? edge_sh[(size_t)(e0 + e) * 4 + c] : 0.f;
  }
  __syncthreads();

  for (int idx = tid; idx < EPW * IN_SZ; idx += 512) {
    int e = idx / IN_SZ, f = idx - e * IN_SZ;
    sIn[e][f] = f2bf(node_attr[(size_t)sDst[e] * IN_SZ + f]);
  }
  for (int idx = tid; idx < EPW * 160; idx += 512) (&sOut[0][0])[idx] = 0.f;
  __syncthreads();

  { // ---- feature construction: 16 workers per edge ----
    const int e = tid >> 4, j = tid & 15;
    const float sh0 = sShs[e][0], sx = sShs[e][1], sy = sShs[e][2], sz = sShs[e][3];
    const float i3 = 0.57735026918962576f, i2 = 0.70710678118654752f;
    for (int i = j; i < 48; i += 16) {
      float v0 = b2f(sIn[e][i]), w0 = b2f(sIn[e][108 + i]);
      sF0[0][i][e] = f2bf(v0 * sh0);
      sF0[1][10 + i][e] = f2bf(w0 * sh0);
      sF1[0][i][0][e] = f2bf(v0 * sx); sF1[0][i][1][e] = f2bf(v0 * sy); sF1[0][i][2][e] = f2bf(v0 * sz);
      sF1[1][20 + i][0][e] = f2bf(w0 * sx); sF1[1][20 + i][1][e] = f2bf(w0 * sy); sF1[1][20 + i][2][e] = f2bf(w0 * sz);
    }
    if (j < 10) {
      const int v = j;
      float ax = b2f(sIn[e][48 + 3 * v]), ay = b2f(sIn[e][48 + 3 * v + 1]), az = b2f(sIn[e][48 + 3 * v + 2]);
      float bx = b2f(sIn[e][78 + 3 * v]), by = b2f(sIn[e][78 + 3 * v + 1]), bz = b2f(sIn[e][78 + 3 * v + 2]);
      sF0[0][48 + v][e] = f2bf((ax * sx + ay * sy + az * sz) * i3);
      sF0[1][v][e]      = f2bf((bx * sx + by * sy + bz * sz) * i3);
      sF1[0][48 + v][0][e] = f2bf(ax * sh0); sF1[0][48 + v][1][e] = f2bf(ay * sh0); sF1[0][48 + v][2][e] = f2bf(az * sh0);
      sF1[0][58 + v][0][e] = f2bf((by * sz - bz * sy) * i2);
      sF1[0][58 + v][1][e] = f2bf((bz * sx - bx * sz) * i2);
      sF1[0][58 + v][2][e] = f2bf((bx * sy - by * sx) * i2);
      sF1[1][v][0][e] = f2bf((ay * sz - az * sy) * i2);
      sF1[1][v][1][e] = f2bf((az * sx - ax * sz) * i2);
      sF1[1][v][2][e] = f2bf((ax * sy - ay * sx) * i2);
      sF1[1][10 + v][0][e] = f2bf(bx * sh0); sF1[1][10 + v][1][e] = f2bf(by * sh0); sF1[1][10 + v][2][e] = f2bf(bz * sh0);
    }
  }
  // zero pad rows (sF0 i=58,59; sF1 i=68,69)
  if (tid < 128) {
    int fam = tid >> 6, i = 58 + ((tid >> 5) & 1), e = tid & 31;
    sF0[fam][i][e] = 0;
  } else if (tid < 128 + 384) {
    int t2 = tid - 128;
    int fam = t2 / 192, r = t2 - fam * 192;
    int i = 68 + (r / 96), r2 = r % 96, cc = r2 >> 5, e = r2 & 31;
    sF1[fam][i][cc][e] = 0;
  }
  __syncthreads();

  const int wv = tid >> 6, l = tid & 15, q = (tid >> 4) & 3;

  // A fragments for both edge halves, registers for whole kernel.
  short8 Af[2][4];
  #pragma unroll
  for (int m = 0; m < 2; ++m) {
    const unsigned short* ar = h_ext + (size_t)(e0 + m * 16 + l) * KE + q * 8;
    #pragma unroll
    for (int s = 0; s < 4; ++s) Af[m][s] = *(const short8*)(ar + s * 32);
  }

  const unsigned short* wbase = W2P + (size_t)l * KE + q * 8;
  auto ldB = [&](short8 (&B)[4], int t) {
    const unsigned short* p = wbase + (size_t)t * (16 * KE);
    #pragma unroll
    for (int s = 0; s < 4; ++s) B[s] = *(const short8*)(p + s * 32);
  };

  if (wv < 4) {
    // ---------------- scalar families (0e / 0o), 3 ob-phases x 30 iters ----------------
    const int sf = wv >> 1;
    const int ibeg = (wv & 1) * 30;
    const int tb = sf ? 310 : 0;
    const int obase = sf ? 108 : 0;
    #pragma unroll 1
    for (int ob = 0; ob < 3; ++ob) {
      float a0[4] = {0.f, 0.f, 0.f, 0.f}, a1[4] = {0.f, 0.f, 0.f, 0.f};
      auto tileof = [&](int ii) { int i = ibeg + ii; if (i >= 58) i = ibeg; return tb + 3 * i + ob; };
      auto body = [&](const short8 (&B)[4], int i) {
        ushort4 f0 = *(const ushort4*)&sF0[sf][i][q * 4];
        ushort4 f1 = *(const ushort4*)&sF0[sf][i][16 + q * 4];
        float4v C0 = {0.f, 0.f, 0.f, 0.f}, C1 = {0.f, 0.f, 0.f, 0.f};
        #pragma unroll
        for (int s = 0; s < 4; ++s) {
          C0 = __builtin_amdgcn_mfma_f32_16x16x32_bf16(Af[0][s], B[s], C0, 0, 0, 0);
          C1 = __builtin_amdgcn_mfma_f32_16x16x32_bf16(Af[1][s], B[s], C1, 0, 0, 0);
        }
        a0[0] += C0[0] * b2f(f0.x); a0[1] += C0[1] * b2f(f0.y);
        a0[2] += C0[2] * b2f(f0.z); a0[3] += C0[3] * b2f(f0.w);
        a1[0] += C1[0] * b2f(f1.x); a1[1] += C1[1] * b2f(f1.y);
        a1[2] += C1[2] * b2f(f1.z); a1[3] += C1[3] * b2f(f1.w);
      };
      short8 B0[4], B1[4];
      ldB(B0, tileof(0));
      #pragma unroll 1
      for (int ii = 0; ii < 30; ii += 2) {
        ldB(B1, tileof(ii + 1));
        body(B0, ibeg + ii);
        ldB(B0, tileof(ii + 2));          // extra last load clamps inside tileof
        body(B1, ibeg + ii + 1);
      }
      const int col = obase + ob * 16 + l;
      #pragma unroll
      for (int r = 0; r < 4; ++r) {
        unsafeAtomicAdd(&sOut[q * 4 + r][col], a0[r]);
        unsafeAtomicAdd(&sOut[16 + q * 4 + r][col], a1[r]);
      }
    }
  } else {
    // ---------------- vector families (1o / 1e), i-half ----------------
    const int vf = (wv >> 1) - 2;
    const int ibeg = (wv & 1) ? 34 : 0;
    const int icnt2 = (wv & 1) ? 36 : 34;
    const int tb = vf ? 242 : 174;
    float r0[4][3] = {{0.f}}, r1[4][3] = {{0.f}};
    auto tileof = [&](int ii) { int i = ibeg + ii; if (i >= 68) i = ibeg; return tb + i; };
    auto body = [&](const short8 (&B)[4], int i) {
      ushort4 g0[3], g1[3];
      #pragma unroll
      for (int cc = 0; cc < 3; ++cc) {
        g0[cc] = *(const ushort4*)&sF1[vf][i][cc][q * 4];
        g1[cc] = *(const ushort4*)&sF1[vf][i][cc][16 + q * 4];
      }
      float4v C0 = {0.f, 0.f, 0.f, 0.f}, C1 = {0.f, 0.f, 0.f, 0.f};
      #pragma unroll
      for (int s = 0; s < 4; ++s) {
        C0 = __builtin_amdgcn_mfma_f32_16x16x32_bf16(Af[0][s], B[s], C0, 0, 0, 0);
        C1 = __builtin_amdgcn_mfma_f32_16x16x32_bf16(Af[1][s], B[s], C1, 0, 0, 0);
      }
      #pragma unroll
      for (int cc = 0; cc < 3; ++cc) {
        r0[0][cc] += C0[0] * b2f(g0[cc].x); r0[1][cc] += C0[1] * b2f(g0[cc].y);
        r0[2][cc] += C0[2] * b2f(g0[cc].z); r0[3][cc] += C0[3] * b2f(g0[cc].w);
        r1[0][cc] += C1[0] * b2f(g1[cc].x); r1[1][cc] += C1[1] * b2f(g1[cc].y);
        r1[2][cc] += C1[2] * b2f(g1[cc].z); r1[3][cc] += C1[3] * b2f(g1[cc].w);
      }
    };
    short8 B0[4], B1[4];
    ldB(B0, tileof(0));
    #pragma unroll 1
    for (int ii = 0; ii < icnt2; ii += 2) {
      ldB(B1, tileof(ii + 1));
      body(B0, ibeg + ii);
      ldB(B0, tileof(ii + 2));
      body(B1, ibeg + ii + 1);
    }
    if (l < 10) {
      const int col = (vf ? 78 : 48) + 3 * l;
      #pragma unroll
      for (int r = 0; r < 4; ++r)
        #pragma unroll
        for (int cc = 0; cc < 3; ++cc) {
          unsafeAtomicAdd(&sOut[q * 4 + r][col + cc], r0[r][cc]);
          unsafeAtomicAdd(&sOut[16 + q * 4 + r][col + cc], r1[r][cc]);
        }
    }
  }
  __syncthreads();

  // ---- scatter to global ----
  const float n58 = 0.13130643285972254f, n68 = 0.12126781251816650f;
  for (int idx = tid; idx < EPW * IN_SZ; idx += 512) {
    int e = idx / IN_SZ, o = idx - e * IN_SZ;
    if (e0 + e < NE) {
      float nrm = (o < 48 || o >= 108) ? n58 : n68;
      unsafeAtomicAdd(&acc[(size_t)sSrc[e] * IN_SZ + o], sOut[e][o] * nrm);
    }
  }
}

// ---------------- Kernel 3: out = acc / max(cnt,1) + node_attr ----------------
__global__ __launch_bounds__(256) void finalize_kernel(
    const float* __restrict__ acc, const int* __restrict__ icnt,
    const float* __restrict__ node_attr, float* __restrict__ out)
{
  int idx = blockIdx.x * 256 + threadIdx.x;
  if (idx < NN * IN_SZ) {
    int n = idx / IN_SZ;
    out[idx] = acc[idx] / fmaxf((float)icnt[n], 1.f) + node_attr[idx];
  }
}

extern "C" void kernel_launch(void* const* d_in, const int* in_sizes, int n_in,
                              void* d_out, int out_size, void* d_ws, size_t ws_size,
                              hipStream_t stream)
{
  const float* node_attr  = (const float*)d_in[0];
  const int*   edge_index = (const int*)d_in[1];
  const float* edge_attr  = (const float*)d_in[2];
  const float* edge_sh    = (const float*)d_in[3];
  const float* W1 = (const float*)d_in[4];
  const float* b1 = (const float*)d_in[5];
  const float* W2 = (const float*)d_in[6];
  const float* b2 = (const float*)d_in[7];
  float* out = (float*)d_out;

  unsigned short* h_ext = (unsigned short*)d_ws;              // 50016 * 128 bf16
  unsigned short* W2P   = h_ext + (size_t)50016 * KE;         // 7744 * 128 bf16
  unsigned short* ea_bf = W2P + (size_t)WP * KE;              // 50000 * 96 bf16 (dead after mlp1)
  unsigned short* W1T   = ea_bf + (size_t)NE * KH;            // 96*96 bf16
  float* acc  = (float*)ea_bf;                                // ALIAS: reused after mlp1
  int*   icnt = (int*)(W1T + KH * KH + 64);                   // 10000 i32 (past W1T)

  cast_kernel<<<(NE * KH / 8 + KH * KH + 255) / 256, 256, 0, stream>>>(edge_attr, W1, ea_bf, W1T);
  w2p_kernel<<<(WP + 255) / 256, 256, 0, stream>>>(W2, b2, W2P);
  mlp1_kernel<<<NE / 16, 384, 0, stream>>>(ea_bf, W1T, b1, h_ext);
  hipMemsetAsync(acc, 0, (size_t)NN * IN_SZ * sizeof(float), stream);
  hipMemsetAsync(icnt, 0, (size_t)NN * sizeof(int), stream);
  hipMemsetAsync(h_ext + (size_t)50000 * KE, 0, (size_t)16 * KE * sizeof(unsigned short), stream);
  tp_kernel<<<(NE + EPW - 1) / EPW, 512, 0, stream>>>(h_ext, node_attr, edge_index,
                                                      edge_sh, W2P, acc, icnt);
  finalize_kernel<<<(NN * IN_SZ + 255) / 256, 256, 0, stream>>>(acc, icnt, node_attr, out);
}

// Round 7
// 532.415 us; speedup vs baseline: 1.0358x; 1.0032x over previous
//
#include <hip/hip_runtime.h>

#define NE 50000
#define NN 10000
#define KH 96
#define KE 128          // padded K: 96 + bias row (=1*b2) + zeros
#define WN 6928
#define WP 7744         // permuted+padded W2 column count = 484 tiles of 16
#define IN_SZ 156
#define EPW 32          // edges per workgroup in tp_kernel

typedef __attribute__((ext_vector_type(8))) short short8;
typedef __attribute__((ext_vector_type(4))) float float4v;

__device__ __forceinline__ unsigned short f2bf(float x) {
  unsigned u = __float_as_uint(x);
  unsigned r = (u + 0x7FFFu + ((u >> 16) & 1u)) >> 16;   // RNE
  return (unsigned short)r;
}
__device__ __forceinline__ float b2f(unsigned short u) {
  return __uint_as_float(((unsigned)u) << 16);
}

// ---------------- Kernel C: cast edge_attr -> bf16 rows; W1 -> bf16 transposed ----------------
__global__ __launch_bounds__(256) void cast_kernel(
    const float* __restrict__ edge_attr, const float* __restrict__ W1,
    unsigned short* __restrict__ ea_bf, unsigned short* __restrict__ W1T)
{
  int idx = blockIdx.x * 256 + threadIdx.x;
  const int nea = NE * KH / 8;                  // 600000
  if (idx < nea) {
    const float* p = edge_attr + (size_t)idx * 8;
    float4 x = *(const float4*)p, y = *(const float4*)(p + 4);
    uint4 pk;
    pk.x = f2bf(x.x) | ((unsigned)f2bf(x.y) << 16);
    pk.y = f2bf(x.z) | ((unsigned)f2bf(x.w) << 16);
    pk.z = f2bf(y.x) | ((unsigned)f2bf(y.y) << 16);
    pk.w = f2bf(y.z) | ((unsigned)f2bf(y.w) << 16);
    *(uint4*)(ea_bf + (size_t)idx * 8) = pk;
  } else {
    int j = idx - nea;
    if (j < KH * KH) {
      int c = j / KH, k = j - c * KH;
      W1T[c * KH + k] = f2bf(W1[k * KH + c]);   // W1T[col][k]
    }
  }
}

// ---------------- Kernel 1: h_ext via MFMA: relu(ea @ W1 + b1), pad cols 96..127 ----------------
__global__ __launch_bounds__(384) void mlp1_kernel(
    const unsigned short* __restrict__ ea_bf, const unsigned short* __restrict__ W1T,
    const float* __restrict__ b1, unsigned short* __restrict__ h_ext)
{
  const int tid = threadIdx.x;
  const int e0 = blockIdx.x * 16;
  const int w = tid >> 6, l = tid & 15, q = (tid >> 4) & 3;

  short8 a[3], b[3];
  #pragma unroll
  for (int s = 0; s < 3; ++s) {
    a[s] = *(const short8*)(ea_bf + (size_t)(e0 + l) * KH + s * 32 + q * 8);
    b[s] = *(const short8*)(W1T + (size_t)(w * 16 + l) * KH + s * 32 + q * 8);
  }
  float4v C = {0.f, 0.f, 0.f, 0.f};
  #pragma unroll
  for (int s = 0; s < 3; ++s)
    C = __builtin_amdgcn_mfma_f32_16x16x32_bf16(a[s], b[s], C, 0, 0, 0);

  float bv = b1[w * 16 + l];
  #pragma unroll
  for (int r = 0; r < 4; ++r)
    h_ext[(size_t)(e0 + q * 4 + r) * KE + w * 16 + l] = f2bf(fmaxf(C[r] + bv, 0.f));

  for (int idx = tid; idx < 16 * 32; idx += 384) {   // pad cols 96..127
    int e = idx >> 5, c = 96 + (idx & 31);
    h_ext[(size_t)(e0 + e) * KE + c] = (c == 96) ? (unsigned short)0x3F80 : (unsigned short)0;
  }
}

// ---------------- Kernel P: permuted W2P[np][k] bf16; thread = np (coalesced col reads) ------
__global__ __launch_bounds__(256) void w2p_kernel(
    const float* __restrict__ W2, const float* __restrict__ b2,
    unsigned short* __restrict__ W2P)
{
  int np = blockIdx.x * 256 + threadIdx.x;
  if (np >= WP) return;
  int c;
  if (np < 2784) c = np;
  else if (np < 3872) { int rel = np - 2784, i = rel >> 4, o = rel & 15; c = (o < 10) ? 2784 + i * 10 + o : -1; }
  else if (np < 4960) { int rel = np - 3872, i = rel >> 4, o = rel & 15; c = (o < 10) ? 3464 + i * 10 + o : -1; }
  else c = 4144 + (np - 4960);

  unsigned short* dst = W2P + (size_t)np * KE;
  if (c < 0) {
    uint4 z = {0u, 0u, 0u, 0u};
    for (int k0 = 0; k0 < KE; k0 += 8) *(uint4*)(dst + k0) = z;
    return;
  }
  const float* src = W2 + c;
  float bvc = b2[c];
  for (int k0 = 0; k0 < KE; k0 += 8) {
    unsigned short o8[8];
    #pragma unroll
    for (int j = 0; j < 8; ++j) {
      int k = k0 + j;
      float v = (k < KH) ? src[(size_t)k * WN] : (k == KH ? bvc : 0.f);
      o8[j] = f2bf(v);
    }
    uint4 pk;
    pk.x = o8[0] | ((unsigned)o8[1] << 16);
    pk.y = o8[2] | ((unsigned)o8[3] << 16);
    pk.z = o8[4] | ((unsigned)o8[5] << 16);
    pk.w = o8[6] | ((unsigned)o8[7] << 16);
    *(uint4*)(dst + k0) = pk;
  }
}

// ---------------- Kernel 2: MFMA w-GEMM fused with TP ----------------
// 512 threads = 8 waves, balanced; LDS caps us at 2 wg/CU = 4 waves/EU.
// CRITICAL: amdgpu_waves_per_eu(4,4) pins the allocator to the occupancy LDS
// allows. launch_bounds(512,4) only sets the MIN; the scheduler still targeted
// 8 waves/EU (<=64 VGPR) and sank every B load to its use -> full L2 latency
// per body, 9.5% MfmaUtil (r4-r6 all ~440us, VGPR_Count=60).
__global__ __attribute__((amdgpu_flat_work_group_size(512, 512), amdgpu_waves_per_eu(4, 4)))
void tp_kernel(
    const unsigned short* __restrict__ h_ext, const float* __restrict__ node_attr,
    const int* __restrict__ edge_index, const float* __restrict__ edge_sh,
    const unsigned short* __restrict__ W2P,
    float* __restrict__ acc, int* __restrict__ icnt)
{
  __shared__ unsigned short sIn[EPW][160];         // bf16 gathered node_attr
  __shared__ float sOut[EPW][160];                 // f32 output staging
  __shared__ unsigned short sF0[2][60][EPW];       // scalar feats bf16 [fam][i][e]
  __shared__ unsigned short sF1[2][70][3][EPW];    // vector feats bf16 [fam][i][cc][e]
  __shared__ float sShs[EPW][4];
  __shared__ int sSrc[EPW], sDst[EPW];

  const int tid = threadIdx.x;
  const int e0 = blockIdx.x * EPW;

  if (tid < EPW) {
    int ok = (e0 + tid) < NE;
    int s = ok ? edge_index[e0 + tid] : 0;
    int d = ok ? edge_index[NE + e0 + tid] : 0;
    sSrc[tid] = s; sDst[tid] = d;
    if (ok) atomicAdd(&icnt[s], 1);
  }
  if (tid >= 128 && tid < 256) {
    int t2 = tid - 128;
    int e = t2 >> 2, c = t2 & 3;
    sShs[e][c] = ((e0 + e) < NE) ? edge_sh[(size_t)(e0 + e) * 4 + c] : 0.f;
  }
  __syncthreads();

  for (int idx = tid; idx < EPW * IN_SZ; idx += 512) {
    int e = idx / IN_SZ, f = idx - e * IN_SZ;
    sIn[e][f] = f2bf(node_attr[(size_t)sDst[e] * IN_SZ + f]);
  }
  for (int idx = tid; idx < EPW * 160; idx += 512) (&sOut[0][0])[idx] = 0.f;
  __syncthreads();

  { // ---- feature construction: 16 workers per edge ----
    const int e = tid >> 4, j = tid & 15;
    const float sh0 = sShs[e][0], sx = sShs[e][1], sy = sShs[e][2], sz = sShs[e][3];
    const float i3 = 0.57735026918962576f, i2 = 0.70710678118654752f;
    for (int i = j; i < 48; i += 16) {
      float v0 = b2f(sIn[e][i]), w0 = b2f(sIn[e][108 + i]);
      sF0[0][i][e] = f2bf(v0 * sh0);
      sF0[1][10 + i][e] = f2bf(w0 * sh0);
      sF1[0][i][0][e] = f2bf(v0 * sx); sF1[0][i][1][e] = f2bf(v0 * sy); sF1[0][i][2][e] = f2bf(v0 * sz);
      sF1[1][20 + i][0][e] = f2bf(w0 * sx); sF1[1][20 + i][1][e] = f2bf(w0 * sy); sF1[1][20 + i][2][e] = f2bf(w0 * sz);
    }
    if (j < 10) {
      const int v = j;
      float ax = b2f(sIn[e][48 + 3 * v]), ay = b2f(sIn[e][48 + 3 * v + 1]), az = b2f(sIn[e][48 + 3 * v + 2]);
      float bx = b2f(sIn[e][78 + 3 * v]), by = b2f(sIn[e][78 + 3 * v + 1]), bz = b2f(sIn[e][78 + 3 * v + 2]);
      sF0[0][48 + v][e] = f2bf((ax * sx + ay * sy + az * sz) * i3);
      sF0[1][v][e]      = f2bf((bx * sx + by * sy + bz * sz) * i3);
      sF1[0][48 + v][0][e] = f2bf(ax * sh0); sF1[0][48 + v][1][e] = f2bf(ay * sh0); sF1[0][48 + v][2][e] = f2bf(az * sh0);
      sF1[0][58 + v][0][e] = f2bf((by * sz - bz * sy) * i2);
      sF1[0][58 + v][1][e] = f2bf((bz * sx - bx * sz) * i2);
      sF1[0][58 + v][2][e] = f2bf((bx * sy - by * sx) * i2);
      sF1[1][v][0][e] = f2bf((ay * sz - az * sy) * i2);
      sF1[1][v][1][e] = f2bf((az * sx - ax * sz) * i2);
      sF1[1][v][2][e] = f2bf((ax * sy - ay * sx) * i2);
      sF1[1][10 + v][0][e] = f2bf(bx * sh0); sF1[1][10 + v][1][e] = f2bf(by * sh0); sF1[1][10 + v][2][e] = f2bf(bz * sh0);
    }
  }
  // zero pad rows (sF0 i=58,59; sF1 i=68,69)
  if (tid < 128) {
    int fam = tid >> 6, i = 58 + ((tid >> 5) & 1), e = tid & 31;
    sF0[fam][i][e] = 0;
  } else if (tid < 128 + 384) {
    int t2 = tid - 128;
    int fam = t2 / 192, r = t2 - fam * 192;
    int i = 68 + (r / 96), r2 = r % 96, cc = r2 >> 5, e = r2 & 31;
    sF1[fam][i][cc][e] = 0;
  }
  __syncthreads();

  const int wv = tid >> 6, l = tid & 15, q = (tid >> 4) & 3;

  // A fragments for both edge halves, registers for whole kernel.
  short8 Af[2][4];
  #pragma unroll
  for (int m = 0; m < 2; ++m) {
    const unsigned short* ar = h_ext + (size_t)(e0 + m * 16 + l) * KE + q * 8;
    #pragma unroll
    for (int s = 0; s < 4; ++s) Af[m][s] = *(const short8*)(ar + s * 32);
  }

  const unsigned short* wbase = W2P + (size_t)l * KE + q * 8;
  auto ldB = [&](short8 (&B)[4], int t) {
    const unsigned short* p = wbase + (size_t)t * (16 * KE);
    #pragma unroll
    for (int s = 0; s < 4; ++s) B[s] = *(const short8*)(p + s * 32);
  };

  if (wv < 4) {
    // ---------------- scalar families (0e / 0o), 3 ob-phases x 30 iters ----------------
    const int sf = wv >> 1;
    const int ibeg = (wv & 1) * 30;
    const int tb = sf ? 310 : 0;
    const int obase = sf ? 108 : 0;
    #pragma unroll 1
    for (int ob = 0; ob < 3; ++ob) {
      float a0[4] = {0.f, 0.f, 0.f, 0.f}, a1[4] = {0.f, 0.f, 0.f, 0.f};
      auto tileof = [&](int ii) { int i = ibeg + ii; if (i >= 58) i = ibeg; return tb + 3 * i + ob; };
      auto body = [&](const short8 (&B)[4], int i) {
        ushort4 f0 = *(const ushort4*)&sF0[sf][i][q * 4];
        ushort4 f1 = *(const ushort4*)&sF0[sf][i][16 + q * 4];
        float4v C0 = {0.f, 0.f, 0.f, 0.f}, C1 = {0.f, 0.f, 0.f, 0.f};
        #pragma unroll
        for (int s = 0; s < 4; ++s) {
          C0 = __builtin_amdgcn_mfma_f32_16x16x32_bf16(Af[0][s], B[s], C0, 0, 0, 0);
          C1 = __builtin_amdgcn_mfma_f32_16x16x32_bf16(Af[1][s], B[s], C1, 0, 0, 0);
        }
        a0[0] += C0[0] * b2f(f0.x); a0[1] += C0[1] * b2f(f0.y);
        a0[2] += C0[2] * b2f(f0.z); a0[3] += C0[3] * b2f(f0.w);
        a1[0] += C1[0] * b2f(f1.x); a1[1] += C1[1] * b2f(f1.y);
        a1[2] += C1[2] * b2f(f1.z); a1[3] += C1[3] * b2f(f1.w);
      };
      short8 B0[4], B1[4];
      ldB(B0, tileof(0));
      #pragma unroll 1
      for (int ii = 0; ii < 30; ii += 2) {
        ldB(B1, tileof(ii + 1));
        body(B0, ibeg + ii);
        ldB(B0, tileof(ii + 2));          // extra last load clamps inside tileof
        body(B1, ibeg + ii + 1);
      }
      const int col = obase + ob * 16 + l;
      #pragma unroll
      for (int r = 0; r < 4; ++r) {
        unsafeAtomicAdd(&sOut[q * 4 + r][col], a0[r]);
        unsafeAtomicAdd(&sOut[16 + q * 4 + r][col], a1[r]);
      }
    }
  } else {
    // ---------------- vector families (1o / 1e), i-half ----------------
    const int vf = (wv >> 1) - 2;
    const int ibeg = (wv & 1) ? 34 : 0;
    const int icnt2 = (wv & 1) ? 36 : 34;
    const int tb = vf ? 242 : 174;
    float r0[4][3] = {{0.f}}, r1[4][3] = {{0.f}};
    auto tileof = [&](int ii) { int i = ibeg + ii; if (i >= 68) i = ibeg; return tb + i; };
    auto body = [&](const short8 (&B)[4], int i) {
      ushort4 g0[3], g1[3];
      #pragma unroll
      for (int cc = 0; cc < 3; ++cc) {
        g0[cc] = *(const ushort4*)&sF1[vf][i][cc][q * 4];
        g1[cc] = *(const ushort4*)&sF1[vf][i][cc][16 + q * 4];
      }
      float4v C0 = {0.f, 0.f, 0.f, 0.f}, C1 = {0.f, 0.f, 0.f, 0.f};
      #pragma unroll
      for (int s = 0; s < 4; ++s) {
        C0 = __builtin_amdgcn_mfma_f32_16x16x32_bf16(Af[0][s], B[s], C0, 0, 0, 0);
        C1 = __builtin_amdgcn_mfma_f32_16x16x32_bf16(Af[1][s], B[s], C1, 0, 0, 0);
      }
      #pragma unroll
      for (int cc = 0; cc < 3; ++cc) {
        r0[0][cc] += C0[0] * b2f(g0[cc].x); r0[1][cc] += C0[1] * b2f(g0[cc].y);
        r0[2][cc] += C0[2] * b2f(g0[cc].z); r0[3][cc] += C0[3] * b2f(g0[cc].w);
        r1[0][cc] += C1[0] * b2f(g1[cc].x); r1[1][cc] += C1[1] * b2f(g1[cc].y);
        r1[2][cc] += C1[2] * b2f(g1[cc].z); r1[3][cc] += C1[3] * b2f(g1[cc].w);
      }
    };
    short8 B0[4], B1[4];
    ldB(B0, tileof(0));
    #pragma unroll 1
    for (int ii = 0; ii < icnt2; ii += 2) {
      ldB(B1, tileof(ii + 1));
      body(B0, ibeg + ii);
      ldB(B0, tileof(ii + 2));
      body(B1, ibeg + ii + 1);
    }
    if (l < 10) {
      const int col = (vf ? 78 : 48) + 3 * l;
      #pragma unroll
      for (int r = 0; r < 4; ++r)
        #pragma unroll
        for (int cc = 0; cc < 3; ++cc) {
          unsafeAtomicAdd(&sOut[q * 4 + r][col + cc], r0[r][cc]);
          unsafeAtomicAdd(&sOut[16 + q * 4 + r][col + cc], r1[r][cc]);
        }
    }
  }
  __syncthreads();

  // ---- scatter to global ----
  const float n58 = 0.13130643285972254f, n68 = 0.12126781251816650f;
  for (int idx = tid; idx < EPW * IN_SZ; idx += 512) {
    int e = idx / IN_SZ, o = idx - e * IN_SZ;
    if (e0 + e < NE) {
      float nrm = (o < 48 || o >= 108) ? n58 : n68;
      unsafeAtomicAdd(&acc[(size_t)sSrc[e] * IN_SZ + o], sOut[e][o] * nrm);
    }
  }
}

// ---------------- Kernel 3: out = acc / max(cnt,1) + node_attr ----------------
__global__ __launch_bounds__(256) void finalize_kernel(
    const float* __restrict__ acc, const int* __restrict__ icnt,
    const float* __restrict__ node_attr, float* __restrict__ out)
{
  int idx = blockIdx.x * 256 + threadIdx.x;
  if (idx < NN * IN_SZ) {
    int n = idx / IN_SZ;
    out[idx] = acc[idx] / fmaxf((float)icnt[n], 1.f) + node_attr[idx];
  }
}

extern "C" void kernel_launch(void* const* d_in, const int* in_sizes, int n_in,
                              void* d_out, int out_size, void* d_ws, size_t ws_size,
                              hipStream_t stream)
{
  const float* node_attr  = (const float*)d_in[0];
  const int*   edge_index = (const int*)d_in[1];
  const float* edge_attr  = (const float*)d_in[2];
  const float* edge_sh    = (const float*)d_in[3];
  const float* W1 = (const float*)d_in[4];
  const float* b1 = (const float*)d_in[5];
  const float* W2 = (const float*)d_in[6];
  const float* b2 = (const float*)d_in[7];
  float* out = (float*)d_out;

  unsigned short* h_ext = (unsigned short*)d_ws;              // 50016 * 128 bf16
  unsigned short* W2P   = h_ext + (size_t)50016 * KE;         // 7744 * 128 bf16
  unsigned short* ea_bf = W2P + (size_t)WP * KE;              // 50000 * 96 bf16 (dead after mlp1)
  unsigned short* W1T   = ea_bf + (size_t)NE * KH;            // 96*96 bf16
  float* acc  = (float*)ea_bf;                                // ALIAS: reused after mlp1
  int*   icnt = (int*)(W1T + KH * KH + 64);                   // 10000 i32 (past W1T)

  cast_kernel<<<(NE * KH / 8 + KH * KH + 255) / 256, 256, 0, stream>>>(edge_attr, W1, ea_bf, W1T);
  w2p_kernel<<<(WP + 255) / 256, 256, 0, stream>>>(W2, b2, W2P);
  mlp1_kernel<<<NE / 16, 384, 0, stream>>>(ea_bf, W1T, b1, h_ext);
  hipMemsetAsync(acc, 0, (size_t)NN * IN_SZ * sizeof(float), stream);
  hipMemsetAsync(icnt, 0, (size_t)NN * sizeof(int), stream);
  hipMemsetAsync(h_ext + (size_t)50000 * KE, 0, (size_t)16 * KE * sizeof(unsigned short), stream);
  tp_kernel<<<(NE + EPW - 1) / EPW, 512, 0, stream>>>(h_ext, node_attr, edge_index,
                                                      edge_sh, W2P, acc, icnt);
  finalize_kernel<<<(NN * IN_SZ + 255) / 256, 256, 0, stream>>>(acc, icnt, node_attr, out);
}

// Round 8
// 528.714 us; speedup vs baseline: 1.0431x; 1.0070x over previous
//
#include <hip/hip_runtime.h>

#define NE 50000
#define NN 10000
#define KH 96
#define KE 128          // padded K: 96 + bias row (=1*b2) + zeros
#define WN 6928
#define WP 7744         // permuted+padded W2 column count = 484 tiles of 16
#define IN_SZ 156
#define EPW 32          // edges per workgroup in tp_kernel

typedef __attribute__((ext_vector_type(8))) short short8;
typedef __attribute__((ext_vector_type(4))) float float4v;

__device__ __forceinline__ unsigned short f2bf(float x) {
  unsigned u = __float_as_uint(x);
  unsigned r = (u + 0x7FFFu + ((u >> 16) & 1u)) >> 16;   // RNE
  return (unsigned short)r;
}
__device__ __forceinline__ float b2f(unsigned short u) {
  return __uint_as_float(((unsigned)u) << 16);
}

// ---- forced-pipeline primitives: volatile asm loads + explicit vmcnt ----
// One B tile = 16 rows x 128 k bf16; per lane 4 x dwordx4 from base+0/64/128/192.
__device__ __forceinline__ void issue4(short8 (&B)[4], const unsigned short* p) {
  asm volatile("global_load_dwordx4 %0, %4, off\n\t"
               "global_load_dwordx4 %1, %4, off offset:64\n\t"
               "global_load_dwordx4 %2, %4, off offset:128\n\t"
               "global_load_dwordx4 %3, %4, off offset:192"
               : "=&v"(B[0]), "=&v"(B[1]), "=&v"(B[2]), "=&v"(B[3])
               : "v"(p));
}
// Wait until <=4 vmem outstanding (the other buffer's 4 loads). Tying B as
// "+v" forces MFMAs that read B to be ordered after this wait.
__device__ __forceinline__ void wait4(short8 (&B)[4]) {
  asm volatile("s_waitcnt vmcnt(4)"
               : "+v"(B[0]), "+v"(B[1]), "+v"(B[2]), "+v"(B[3]));
}
__device__ __forceinline__ void wait0(short8 (&B)[4]) {
  asm volatile("s_waitcnt vmcnt(0)"
               : "+v"(B[0]), "+v"(B[1]), "+v"(B[2]), "+v"(B[3]));
}

// ---------------- Kernel C: cast edge_attr -> bf16 rows; W1 -> bf16 transposed ----------------
__global__ __launch_bounds__(256) void cast_kernel(
    const float* __restrict__ edge_attr, const float* __restrict__ W1,
    unsigned short* __restrict__ ea_bf, unsigned short* __restrict__ W1T)
{
  int idx = blockIdx.x * 256 + threadIdx.x;
  const int nea = NE * KH / 8;                  // 600000
  if (idx < nea) {
    const float* p = edge_attr + (size_t)idx * 8;
    float4 x = *(const float4*)p, y = *(const float4*)(p + 4);
    uint4 pk;
    pk.x = f2bf(x.x) | ((unsigned)f2bf(x.y) << 16);
    pk.y = f2bf(x.z) | ((unsigned)f2bf(x.w) << 16);
    pk.z = f2bf(y.x) | ((unsigned)f2bf(y.y) << 16);
    pk.w = f2bf(y.z) | ((unsigned)f2bf(y.w) << 16);
    *(uint4*)(ea_bf + (size_t)idx * 8) = pk;
  } else {
    int j = idx - nea;
    if (j < KH * KH) {
      int c = j / KH, k = j - c * KH;
      W1T[c * KH + k] = f2bf(W1[k * KH + c]);   // W1T[col][k]
    }
  }
}

// ---------------- Kernel 1: h_ext via MFMA: relu(ea @ W1 + b1), pad cols 96..127 ----------------
__global__ __launch_bounds__(384) void mlp1_kernel(
    const unsigned short* __restrict__ ea_bf, const unsigned short* __restrict__ W1T,
    const float* __restrict__ b1, unsigned short* __restrict__ h_ext)
{
  const int tid = threadIdx.x;
  const int e0 = blockIdx.x * 16;
  const int w = tid >> 6, l = tid & 15, q = (tid >> 4) & 3;

  short8 a[3], b[3];
  #pragma unroll
  for (int s = 0; s < 3; ++s) {
    a[s] = *(const short8*)(ea_bf + (size_t)(e0 + l) * KH + s * 32 + q * 8);
    b[s] = *(const short8*)(W1T + (size_t)(w * 16 + l) * KH + s * 32 + q * 8);
  }
  float4v C = {0.f, 0.f, 0.f, 0.f};
  #pragma unroll
  for (int s = 0; s < 3; ++s)
    C = __builtin_amdgcn_mfma_f32_16x16x32_bf16(a[s], b[s], C, 0, 0, 0);

  float bv = b1[w * 16 + l];
  #pragma unroll
  for (int r = 0; r < 4; ++r)
    h_ext[(size_t)(e0 + q * 4 + r) * KE + w * 16 + l] = f2bf(fmaxf(C[r] + bv, 0.f));

  for (int idx = tid; idx < 16 * 32; idx += 384) {   // pad cols 96..127
    int e = idx >> 5, c = 96 + (idx & 31);
    h_ext[(size_t)(e0 + e) * KE + c] = (c == 96) ? (unsigned short)0x3F80 : (unsigned short)0;
  }
}

// ---------------- Kernel P: permuted W2P[np][k] bf16; thread = np (coalesced col reads) ------
__global__ __launch_bounds__(256) void w2p_kernel(
    const float* __restrict__ W2, const float* __restrict__ b2,
    unsigned short* __restrict__ W2P)
{
  int np = blockIdx.x * 256 + threadIdx.x;
  if (np >= WP) return;
  int c;
  if (np < 2784) c = np;
  else if (np < 3872) { int rel = np - 2784, i = rel >> 4, o = rel & 15; c = (o < 10) ? 2784 + i * 10 + o : -1; }
  else if (np < 4960) { int rel = np - 3872, i = rel >> 4, o = rel & 15; c = (o < 10) ? 3464 + i * 10 + o : -1; }
  else c = 4144 + (np - 4960);

  unsigned short* dst = W2P + (size_t)np * KE;
  if (c < 0) {
    uint4 z = {0u, 0u, 0u, 0u};
    for (int k0 = 0; k0 < KE; k0 += 8) *(uint4*)(dst + k0) = z;
    return;
  }
  const float* src = W2 + c;
  float bvc = b2[c];
  for (int k0 = 0; k0 < KE; k0 += 8) {
    unsigned short o8[8];
    #pragma unroll
    for (int j = 0; j < 8; ++j) {
      int k = k0 + j;
      float v = (k < KH) ? src[(size_t)k * WN] : (k == KH ? bvc : 0.f);
      o8[j] = f2bf(v);
    }
    uint4 pk;
    pk.x = o8[0] | ((unsigned)o8[1] << 16);
    pk.y = o8[2] | ((unsigned)o8[3] << 16);
    pk.z = o8[4] | ((unsigned)o8[5] << 16);
    pk.w = o8[6] | ((unsigned)o8[7] << 16);
    *(uint4*)(dst + k0) = pk;
  }
}

// ---------------- Kernel 2: MFMA w-GEMM fused with TP; asm-forced B pipeline ----------------
// 512 threads = 8 waves, balanced. launch_bounds(512,2): 256-VGPR budget so the
// asm-pinned pipeline (~100 regs) never spills. r4-r7 all ~441us with VGPR=60:
// the compiler sank every B load to its use (full L2 latency per body). The
// asm loads + tied s_waitcnt vmcnt(4) make that transformation impossible.
__global__ __launch_bounds__(512, 2) void tp_kernel(
    const unsigned short* __restrict__ h_ext, const float* __restrict__ node_attr,
    const int* __restrict__ edge_index, const float* __restrict__ edge_sh,
    const unsigned short* __restrict__ W2P,
    float* __restrict__ acc, int* __restrict__ icnt)
{
  __shared__ unsigned short sIn[EPW][160];         // bf16 gathered node_attr
  __shared__ float sOut[EPW][160];                 // f32 output staging
  __shared__ unsigned short sF0[2][60][EPW];       // scalar feats bf16 [fam][i][e]
  __shared__ unsigned short sF1[2][70][3][EPW];    // vector feats bf16 [fam][i][cc][e]
  __shared__ float sShs[EPW][4];
  __shared__ int sSrc[EPW], sDst[EPW];

  const int tid = threadIdx.x;
  const int e0 = blockIdx.x * EPW;

  if (tid < EPW) {
    int ok = (e0 + tid) < NE;
    int s = ok ? edge_index[e0 + tid] : 0;
    int d = ok ? edge_index[NE + e0 + tid] : 0;
    sSrc[tid] = s; sDst[tid] = d;
    if (ok) atomicAdd(&icnt[s], 1);
  }
  if (tid >= 128 && tid < 256) {
    int t2 = tid - 128;
    int e = t2 >> 2, c = t2 & 3;
    sShs[e][c] = ((e0 + e) < NE) ? edge_sh[(size_t)(e0 + e) * 4 + c] : 0.f;
  }
  __syncthreads();

  for (int idx = tid; idx < EPW * IN_SZ; idx += 512) {
    int e = idx / IN_SZ, f = idx - e * IN_SZ;
    sIn[e][f] = f2bf(node_attr[(size_t)sDst[e] * IN_SZ + f]);
  }
  for (int idx = tid; idx < EPW * 160; idx += 512) (&sOut[0][0])[idx] = 0.f;
  __syncthreads();

  { // ---- feature construction: 16 workers per edge ----
    const int e = tid >> 4, j = tid & 15;
    const float sh0 = sShs[e][0], sx = sShs[e][1], sy = sShs[e][2], sz = sShs[e][3];
    const float i3 = 0.57735026918962576f, i2 = 0.70710678118654752f;
    for (int i = j; i < 48; i += 16) {
      float v0 = b2f(sIn[e][i]), w0 = b2f(sIn[e][108 + i]);
      sF0[0][i][e] = f2bf(v0 * sh0);
      sF0[1][10 + i][e] = f2bf(w0 * sh0);
      sF1[0][i][0][e] = f2bf(v0 * sx); sF1[0][i][1][e] = f2bf(v0 * sy); sF1[0][i][2][e] = f2bf(v0 * sz);
      sF1[1][20 + i][0][e] = f2bf(w0 * sx); sF1[1][20 + i][1][e] = f2bf(w0 * sy); sF1[1][20 + i][2][e] = f2bf(w0 * sz);
    }
    if (j < 10) {
      const int v = j;
      float ax = b2f(sIn[e][48 + 3 * v]), ay = b2f(sIn[e][48 + 3 * v + 1]), az = b2f(sIn[e][48 + 3 * v + 2]);
      float bx = b2f(sIn[e][78 + 3 * v]), by = b2f(sIn[e][78 + 3 * v + 1]), bz = b2f(sIn[e][78 + 3 * v + 2]);
      sF0[0][48 + v][e] = f2bf((ax * sx + ay * sy + az * sz) * i3);
      sF0[1][v][e]      = f2bf((bx * sx + by * sy + bz * sz) * i3);
      sF1[0][48 + v][0][e] = f2bf(ax * sh0); sF1[0][48 + v][1][e] = f2bf(ay * sh0); sF1[0][48 + v][2][e] = f2bf(az * sh0);
      sF1[0][58 + v][0][e] = f2bf((by * sz - bz * sy) * i2);
      sF1[0][58 + v][1][e] = f2bf((bz * sx - bx * sz) * i2);
      sF1[0][58 + v][2][e] = f2bf((bx * sy - by * sx) * i2);
      sF1[1][v][0][e] = f2bf((ay * sz - az * sy) * i2);
      sF1[1][v][1][e] = f2bf((az * sx - ax * sz) * i2);
      sF1[1][v][2][e] = f2bf((ax * sy - ay * sx) * i2);
      sF1[1][10 + v][0][e] = f2bf(bx * sh0); sF1[1][10 + v][1][e] = f2bf(by * sh0); sF1[1][10 + v][2][e] = f2bf(bz * sh0);
    }
  }
  // zero pad rows (sF0 i=58,59; sF1 i=68,69)
  if (tid < 128) {
    int fam = tid >> 6, i = 58 + ((tid >> 5) & 1), e = tid & 31;
    sF0[fam][i][e] = 0;
  } else if (tid < 128 + 384) {
    int t2 = tid - 128;
    int fam = t2 / 192, r = t2 - fam * 192;
    int i = 68 + (r / 96), r2 = r % 96, cc = r2 >> 5, e = r2 & 31;
    sF1[fam][i][cc][e] = 0;
  }
  __syncthreads();

  const int wv = tid >> 6, l = tid & 15, q = (tid >> 4) & 3;

  // A fragments for both edge halves, registers for whole kernel.
  short8 Af[2][4];
  #pragma unroll
  for (int m = 0; m < 2; ++m) {
    const unsigned short* ar = h_ext + (size_t)(e0 + m * 16 + l) * KE + q * 8;
    #pragma unroll
    for (int s = 0; s < 4; ++s) Af[m][s] = *(const short8*)(ar + s * 32);
  }

  const unsigned short* wrow = W2P + (size_t)l * KE + q * 8;
  short8 Ba[4], Bb[4];

  if (wv < 4) {
    // ---------------- scalar families (0e / 0o), 3 ob-phases x 30 iters ----------------
    const int sf = wv >> 1;
    const int ibeg = (wv & 1) * 30;
    const int tb = sf ? 310 : 0;
    const int obase = sf ? 108 : 0;
    #pragma unroll 1
    for (int ob = 0; ob < 3; ++ob) {
      float a0[4] = {0.f, 0.f, 0.f, 0.f}, a1[4] = {0.f, 0.f, 0.f, 0.f};
      auto addr = [&](int ii) {
        int i = ibeg + ii; if (i >= 58) i = ibeg;          // pad rows load a safe tile
        return wrow + (size_t)(tb + 3 * i + ob) * 2048;
      };
      auto body = [&](const short8 (&B)[4], int ii) {
        int i = ibeg + ii;
        ushort4 f0 = *(const ushort4*)&sF0[sf][i][q * 4];
        ushort4 f1 = *(const ushort4*)&sF0[sf][i][16 + q * 4];
        float4v C0 = {0.f, 0.f, 0.f, 0.f}, C1 = {0.f, 0.f, 0.f, 0.f};
        #pragma unroll
        for (int s = 0; s < 4; ++s) {
          C0 = __builtin_amdgcn_mfma_f32_16x16x32_bf16(Af[0][s], B[s], C0, 0, 0, 0);
          C1 = __builtin_amdgcn_mfma_f32_16x16x32_bf16(Af[1][s], B[s], C1, 0, 0, 0);
        }
        a0[0] += C0[0] * b2f(f0.x); a0[1] += C0[1] * b2f(f0.y);
        a0[2] += C0[2] * b2f(f0.z); a0[3] += C0[3] * b2f(f0.w);
        a1[0] += C1[0] * b2f(f1.x); a1[1] += C1[1] * b2f(f1.y);
        a1[2] += C1[2] * b2f(f1.z); a1[3] += C1[3] * b2f(f1.w);
      };
      issue4(Ba, addr(0));
      issue4(Bb, addr(1));
      #pragma unroll 1
      for (int ii = 0; ii < 28; ii += 2) {
        wait4(Ba); body(Ba, ii);     issue4(Ba, addr(ii + 2));
        wait4(Bb); body(Bb, ii + 1); issue4(Bb, addr(ii + 3));
      }
      wait4(Ba); body(Ba, 28);
      wait0(Bb); body(Bb, 29);
      const int col = obase + ob * 16 + l;
      #pragma unroll
      for (int r = 0; r < 4; ++r) {
        unsafeAtomicAdd(&sOut[q * 4 + r][col], a0[r]);
        unsafeAtomicAdd(&sOut[16 + q * 4 + r][col], a1[r]);
      }
    }
  } else {
    // ---------------- vector families (1o / 1e), i-half ----------------
    const int vf = (wv >> 1) - 2;
    const int ibeg = (wv & 1) ? 34 : 0;
    const int N = (wv & 1) ? 36 : 34;
    const int tb = vf ? 242 : 174;
    float r0[4][3] = {{0.f}}, r1[4][3] = {{0.f}};
    auto addr = [&](int ii) {
      int i = ibeg + ii; if (i >= 68) i = ibeg;
      return wrow + (size_t)(tb + i) * 2048;
    };
    auto body = [&](const short8 (&B)[4], int ii) {
      int i = ibeg + ii;
      ushort4 g0[3], g1[3];
      #pragma unroll
      for (int cc = 0; cc < 3; ++cc) {
        g0[cc] = *(const ushort4*)&sF1[vf][i][cc][q * 4];
        g1[cc] = *(const ushort4*)&sF1[vf][i][cc][16 + q * 4];
      }
      float4v C0 = {0.f, 0.f, 0.f, 0.f}, C1 = {0.f, 0.f, 0.f, 0.f};
      #pragma unroll
      for (int s = 0; s < 4; ++s) {
        C0 = __builtin_amdgcn_mfma_f32_16x16x32_bf16(Af[0][s], B[s], C0, 0, 0, 0);
        C1 = __builtin_amdgcn_mfma_f32_16x16x32_bf16(Af[1][s], B[s], C1, 0, 0, 0);
      }
      #pragma unroll
      for (int cc = 0; cc < 3; ++cc) {
        r0[0][cc] += C0[0] * b2f(g0[cc].x); r0[1][cc] += C0[1] * b2f(g0[cc].y);
        r0[2][cc] += C0[2] * b2f(g0[cc].z); r0[3][cc] += C0[3] * b2f(g0[cc].w);
        r1[0][cc] += C1[0] * b2f(g1[cc].x); r1[1][cc] += C1[1] * b2f(g1[cc].y);
        r1[2][cc] += C1[2] * b2f(g1[cc].z); r1[3][cc] += C1[3] * b2f(g1[cc].w);
      }
    };
    issue4(Ba, addr(0));
    issue4(Bb, addr(1));
    #pragma unroll 1
    for (int ii = 0; ii < N - 2; ii += 2) {
      wait4(Ba); body(Ba, ii);     issue4(Ba, addr(ii + 2));
      wait4(Bb); body(Bb, ii + 1); issue4(Bb, addr(ii + 3));
    }
    wait4(Ba); body(Ba, N - 2);
    wait0(Bb); body(Bb, N - 1);
    if (l < 10) {
      const int col = (vf ? 78 : 48) + 3 * l;
      #pragma unroll
      for (int r = 0; r < 4; ++r)
        #pragma unroll
        for (int cc = 0; cc < 3; ++cc) {
          unsafeAtomicAdd(&sOut[q * 4 + r][col + cc], r0[r][cc]);
          unsafeAtomicAdd(&sOut[16 + q * 4 + r][col + cc], r1[r][cc]);
        }
    }
  }
  __syncthreads();

  // ---- scatter to global ----
  const float n58 = 0.13130643285972254f, n68 = 0.12126781251816650f;
  for (int idx = tid; idx < EPW * IN_SZ; idx += 512) {
    int e = idx / IN_SZ, o = idx - e * IN_SZ;
    if (e0 + e < NE) {
      float nrm = (o < 48 || o >= 108) ? n58 : n68;
      unsafeAtomicAdd(&acc[(size_t)sSrc[e] * IN_SZ + o], sOut[e][o] * nrm);
    }
  }
}

// ---------------- Kernel 3: out = acc / max(cnt,1) + node_attr ----------------
__global__ __launch_bounds__(256) void finalize_kernel(
    const float* __restrict__ acc, const int* __restrict__ icnt,
    const float* __restrict__ node_attr, float* __restrict__ out)
{
  int idx = blockIdx.x * 256 + threadIdx.x;
  if (idx < NN * IN_SZ) {
    int n = idx / IN_SZ;
    out[idx] = acc[idx] / fmaxf((float)icnt[n], 1.f) + node_attr[idx];
  }
}

extern "C" void kernel_launch(void* const* d_in, const int* in_sizes, int n_in,
                              void* d_out, int out_size, void* d_ws, size_t ws_size,
                              hipStream_t stream)
{
  const float* node_attr  = (const float*)d_in[0];
  const int*   edge_index = (const int*)d_in[1];
  const float* edge_attr  = (const float*)d_in[2];
  const float* edge_sh    = (const float*)d_in[3];
  const float* W1 = (const float*)d_in[4];
  const float* b1 = (const float*)d_in[5];
  const float* W2 = (const float*)d_in[6];
  const float* b2 = (const float*)d_in[7];
  float* out = (float*)d_out;

  unsigned short* h_ext = (unsigned short*)d_ws;              // 50016 * 128 bf16
  unsigned short* W2P   = h_ext + (size_t)50016 * KE;         // 7744 * 128 bf16
  unsigned short* ea_bf = W2P + (size_t)WP * KE;              // 50000 * 96 bf16 (dead after mlp1)
  unsigned short* W1T   = ea_bf + (size_t)NE * KH;            // 96*96 bf16
  float* acc  = (float*)ea_bf;                                // ALIAS: reused after mlp1
  int*   icnt = (int*)(W1T + KH * KH + 64);                   // 10000 i32 (past W1T)

  cast_kernel<<<(NE * KH / 8 + KH * KH + 255) / 256, 256, 0, stream>>>(edge_attr, W1, ea_bf, W1T);
  w2p_kernel<<<(WP + 255) / 256, 256, 0, stream>>>(W2, b2, W2P);
  mlp1_kernel<<<NE / 16, 384, 0, stream>>>(ea_bf, W1T, b1, h_ext);
  hipMemsetAsync(acc, 0, (size_t)NN * IN_SZ * sizeof(float), stream);
  hipMemsetAsync(icnt, 0, (size_t)NN * sizeof(int), stream);
  hipMemsetAsync(h_ext + (size_t)50000 * KE, 0, (size_t)16 * KE * sizeof(unsigned short), stream);
  tp_kernel<<<(NE + EPW - 1) / EPW, 512, 0, stream>>>(h_ext, node_attr, edge_index,
                                                      edge_sh, W2P, acc, icnt);
  finalize_kernel<<<(NN * IN_SZ + 255) / 256, 256, 0, stream>>>(acc, icnt, node_attr, out);
}

// Round 9
// 326.625 us; speedup vs baseline: 1.6885x; 1.6187x over previous
//
#include <hip/hip_runtime.h>

#define NE 50000
#define NN 10000
#define KH 96
#define KE 128          // padded K: 96 + bias row (=1*b2) + zeros
#define WN 6928
#define WP 7744         // permuted+padded W2 column count = 484 tiles of 16
#define NTILE 484
#define IN_SZ 156
#define EPW 32          // edges per workgroup in tp_kernel

typedef __attribute__((ext_vector_type(8))) short short8;
typedef __attribute__((ext_vector_type(4))) float float4v;

__device__ __forceinline__ unsigned short f2bf(float x) {
  unsigned u = __float_as_uint(x);
  unsigned r = (u + 0x7FFFu + ((u >> 16) & 1u)) >> 16;   // RNE
  return (unsigned short)r;
}
__device__ __forceinline__ float b2f(unsigned short u) {
  return __uint_as_float(((unsigned)u) << 16);
}

// ---- forced-pipeline primitives: volatile asm loads + explicit vmcnt ----
// One B tile = 4KB contiguous in W2PT; lane reads base + s*1024 + lane*16:
// perfectly coalesced 1KB per instruction (r4-r8 used a 256B-strided layout:
// 16 scattered 64B segments per instr -> ~87 cyc/instr VMEM serialization,
// the invariant 440us bottleneck).
__device__ __forceinline__ void issue4(short8 (&B)[4], const unsigned short* p) {
  asm volatile("global_load_dwordx4 %0, %4, off\n\t"
               "global_load_dwordx4 %1, %4, off offset:1024\n\t"
               "global_load_dwordx4 %2, %4, off offset:2048\n\t"
               "global_load_dwordx4 %3, %4, off offset:3072"
               : "=&v"(B[0]), "=&v"(B[1]), "=&v"(B[2]), "=&v"(B[3])
               : "v"(p));
}
__device__ __forceinline__ void wait4(short8 (&B)[4]) {
  asm volatile("s_waitcnt vmcnt(4)"
               : "+v"(B[0]), "+v"(B[1]), "+v"(B[2]), "+v"(B[3]));
}
__device__ __forceinline__ void wait0(short8 (&B)[4]) {
  asm volatile("s_waitcnt vmcnt(0)"
               : "+v"(B[0]), "+v"(B[1]), "+v"(B[2]), "+v"(B[3]));
}

// ---------------- Kernel C: cast edge_attr -> bf16 rows; W1 -> bf16 transposed ----------------
__global__ __launch_bounds__(256) void cast_kernel(
    const float* __restrict__ edge_attr, const float* __restrict__ W1,
    unsigned short* __restrict__ ea_bf, unsigned short* __restrict__ W1T)
{
  int idx = blockIdx.x * 256 + threadIdx.x;
  const int nea = NE * KH / 8;                  // 600000
  if (idx < nea) {
    const float* p = edge_attr + (size_t)idx * 8;
    float4 x = *(const float4*)p, y = *(const float4*)(p + 4);
    uint4 pk;
    pk.x = f2bf(x.x) | ((unsigned)f2bf(x.y) << 16);
    pk.y = f2bf(x.z) | ((unsigned)f2bf(x.w) << 16);
    pk.z = f2bf(y.x) | ((unsigned)f2bf(y.y) << 16);
    pk.w = f2bf(y.z) | ((unsigned)f2bf(y.w) << 16);
    *(uint4*)(ea_bf + (size_t)idx * 8) = pk;
  } else {
    int j = idx - nea;
    if (j < KH * KH) {
      int c = j / KH, k = j - c * KH;
      W1T[c * KH + k] = f2bf(W1[k * KH + c]);   // W1T[col][k]
    }
  }
}

// ---------------- Kernel 1: h_ext via MFMA: relu(ea @ W1 + b1), pad cols 96..127 ----------------
__global__ __launch_bounds__(384) void mlp1_kernel(
    const unsigned short* __restrict__ ea_bf, const unsigned short* __restrict__ W1T,
    const float* __restrict__ b1, unsigned short* __restrict__ h_ext)
{
  const int tid = threadIdx.x;
  const int e0 = blockIdx.x * 16;
  const int w = tid >> 6, l = tid & 15, q = (tid >> 4) & 3;

  short8 a[3], b[3];
  #pragma unroll
  for (int s = 0; s < 3; ++s) {
    a[s] = *(const short8*)(ea_bf + (size_t)(e0 + l) * KH + s * 32 + q * 8);
    b[s] = *(const short8*)(W1T + (size_t)(w * 16 + l) * KH + s * 32 + q * 8);
  }
  float4v C = {0.f, 0.f, 0.f, 0.f};
  #pragma unroll
  for (int s = 0; s < 3; ++s)
    C = __builtin_amdgcn_mfma_f32_16x16x32_bf16(a[s], b[s], C, 0, 0, 0);

  float bv = b1[w * 16 + l];
  #pragma unroll
  for (int r = 0; r < 4; ++r)
    h_ext[(size_t)(e0 + q * 4 + r) * KE + w * 16 + l] = f2bf(fmaxf(C[r] + bv, 0.f));

  for (int idx = tid; idx < 16 * 32; idx += 384) {   // pad cols 96..127
    int e = idx >> 5, c = 96 + (idx & 31);
    h_ext[(size_t)(e0 + e) * KE + c] = (c == 96) ? (unsigned short)0x3F80 : (unsigned short)0;
  }
}

// ---------------- Kernel P: tile-major lane-ordered W2PT ----------------
// W2PT short index = t*2048 + s*512 + lane*8; lane = q*16+l holds
// B[n = t*16+l][k = s*32+q*8 .. +8]  (bf16; k=96 -> b2, k>96 -> 0).
// Column permutation np -> original W2 column c as before.
__global__ __launch_bounds__(256) void w2pt_kernel(
    const float* __restrict__ W2, const float* __restrict__ b2,
    unsigned short* __restrict__ W2PT)
{
  int gid = blockIdx.x * 256 + threadIdx.x;     // (t, s, lane)
  if (gid >= NTILE * 256) return;
  int lane = gid & 63, s = (gid >> 6) & 3, t = gid >> 8;
  int l = lane & 15, q = lane >> 4;
  int np = t * 16 + l;
  int c;
  if (np < 2784) c = np;
  else if (np < 3872) { int rel = np - 2784, i = rel >> 4, o = rel & 15; c = (o < 10) ? 2784 + i * 10 + o : -1; }
  else if (np < 4960) { int rel = np - 3872, i = rel >> 4, o = rel & 15; c = (o < 10) ? 3464 + i * 10 + o : -1; }
  else c = 4144 + (np - 4960);

  int kbase = s * 32 + q * 8;
  unsigned short o8[8];
  #pragma unroll
  for (int j = 0; j < 8; ++j) {
    int k = kbase + j;
    float v = 0.f;
    if (c >= 0) v = (k < KH) ? W2[(size_t)k * WN + c] : (k == KH ? b2[c] : 0.f);
    o8[j] = f2bf(v);
  }
  uint4 pk;
  pk.x = o8[0] | ((unsigned)o8[1] << 16);
  pk.y = o8[2] | ((unsigned)o8[3] << 16);
  pk.z = o8[4] | ((unsigned)o8[5] << 16);
  pk.w = o8[6] | ((unsigned)o8[7] << 16);
  *(uint4*)(W2PT + (size_t)gid * 8) = pk;
}

// ---------------- Kernel 2: MFMA w-GEMM fused with TP; coalesced B tiles ----------------
__global__ __launch_bounds__(512, 2) void tp_kernel(
    const unsigned short* __restrict__ h_ext, const float* __restrict__ node_attr,
    const int* __restrict__ edge_index, const float* __restrict__ edge_sh,
    const unsigned short* __restrict__ W2PT,
    float* __restrict__ acc, int* __restrict__ icnt)
{
  __shared__ unsigned short sIn[EPW][160];         // bf16 gathered node_attr
  __shared__ float sOut[EPW][160];                 // f32 output staging
  __shared__ unsigned short sF0[2][60][EPW];       // scalar feats bf16 [fam][i][e]
  __shared__ unsigned short sF1[2][70][3][EPW];    // vector feats bf16 [fam][i][cc][e]
  __shared__ float sShs[EPW][4];
  __shared__ int sSrc[EPW], sDst[EPW];

  const int tid = threadIdx.x;
  const int e0 = blockIdx.x * EPW;

  if (tid < EPW) {
    int ok = (e0 + tid) < NE;
    int s = ok ? edge_index[e0 + tid] : 0;
    int d = ok ? edge_index[NE + e0 + tid] : 0;
    sSrc[tid] = s; sDst[tid] = d;
    if (ok) atomicAdd(&icnt[s], 1);
  }
  if (tid >= 128 && tid < 256) {
    int t2 = tid - 128;
    int e = t2 >> 2, c = t2 & 3;
    sShs[e][c] = ((e0 + e) < NE) ? edge_sh[(size_t)(e0 + e) * 4 + c] : 0.f;
  }
  __syncthreads();

  for (int idx = tid; idx < EPW * IN_SZ; idx += 512) {
    int e = idx / IN_SZ, f = idx - e * IN_SZ;
    sIn[e][f] = f2bf(node_attr[(size_t)sDst[e] * IN_SZ + f]);
  }
  for (int idx = tid; idx < EPW * 160; idx += 512) (&sOut[0][0])[idx] = 0.f;
  __syncthreads();

  { // ---- feature construction: 16 workers per edge ----
    const int e = tid >> 4, j = tid & 15;
    const float sh0 = sShs[e][0], sx = sShs[e][1], sy = sShs[e][2], sz = sShs[e][3];
    const float i3 = 0.57735026918962576f, i2 = 0.70710678118654752f;
    for (int i = j; i < 48; i += 16) {
      float v0 = b2f(sIn[e][i]), w0 = b2f(sIn[e][108 + i]);
      sF0[0][i][e] = f2bf(v0 * sh0);
      sF0[1][10 + i][e] = f2bf(w0 * sh0);
      sF1[0][i][0][e] = f2bf(v0 * sx); sF1[0][i][1][e] = f2bf(v0 * sy); sF1[0][i][2][e] = f2bf(v0 * sz);
      sF1[1][20 + i][0][e] = f2bf(w0 * sx); sF1[1][20 + i][1][e] = f2bf(w0 * sy); sF1[1][20 + i][2][e] = f2bf(w0 * sz);
    }
    if (j < 10) {
      const int v = j;
      float ax = b2f(sIn[e][48 + 3 * v]), ay = b2f(sIn[e][48 + 3 * v + 1]), az = b2f(sIn[e][48 + 3 * v + 2]);
      float bx = b2f(sIn[e][78 + 3 * v]), by = b2f(sIn[e][78 + 3 * v + 1]), bz = b2f(sIn[e][78 + 3 * v + 2]);
      sF0[0][48 + v][e] = f2bf((ax * sx + ay * sy + az * sz) * i3);
      sF0[1][v][e]      = f2bf((bx * sx + by * sy + bz * sz) * i3);
      sF1[0][48 + v][0][e] = f2bf(ax * sh0); sF1[0][48 + v][1][e] = f2bf(ay * sh0); sF1[0][48 + v][2][e] = f2bf(az * sh0);
      sF1[0][58 + v][0][e] = f2bf((by * sz - bz * sy) * i2);
      sF1[0][58 + v][1][e] = f2bf((bz * sx - bx * sz) * i2);
      sF1[0][58 + v][2][e] = f2bf((bx * sy - by * sx) * i2);
      sF1[1][v][0][e] = f2bf((ay * sz - az * sy) * i2);
      sF1[1][v][1][e] = f2bf((az * sx - ax * sz) * i2);
      sF1[1][v][2][e] = f2bf((ax * sy - ay * sx) * i2);
      sF1[1][10 + v][0][e] = f2bf(bx * sh0); sF1[1][10 + v][1][e] = f2bf(by * sh0); sF1[1][10 + v][2][e] = f2bf(bz * sh0);
    }
  }
  // zero pad rows (sF0 i=58,59; sF1 i=68,69)
  if (tid < 128) {
    int fam = tid >> 6, i = 58 + ((tid >> 5) & 1), e = tid & 31;
    sF0[fam][i][e] = 0;
  } else if (tid < 128 + 384) {
    int t2 = tid - 128;
    int fam = t2 / 192, r = t2 - fam * 192;
    int i = 68 + (r / 96), r2 = r % 96, cc = r2 >> 5, e = r2 & 31;
    sF1[fam][i][cc][e] = 0;
  }
  __syncthreads();

  const int wv = tid >> 6, l = tid & 15, q = (tid >> 4) & 3;

  // A fragments for both edge halves, registers for whole kernel.
  short8 Af[2][4];
  #pragma unroll
  for (int m = 0; m < 2; ++m) {
    const unsigned short* ar = h_ext + (size_t)(e0 + m * 16 + l) * KE + q * 8;
    #pragma unroll
    for (int s = 0; s < 4; ++s) Af[m][s] = *(const short8*)(ar + s * 32);
  }

  const unsigned short* wlane = W2PT + (size_t)(tid & 63) * 8;   // coalesced: lane*16B
  short8 Ba[4], Bb[4];

  if (wv < 4) {
    // ---------------- scalar families (0e / 0o), 3 ob-phases x 30 iters ----------------
    const int sf = wv >> 1;
    const int ibeg = (wv & 1) * 30;
    const int tb = sf ? 310 : 0;
    const int obase = sf ? 108 : 0;
    #pragma unroll 1
    for (int ob = 0; ob < 3; ++ob) {
      float a0[4] = {0.f, 0.f, 0.f, 0.f}, a1[4] = {0.f, 0.f, 0.f, 0.f};
      auto addr = [&](int ii) {
        int i = ibeg + ii; if (i >= 58) i = ibeg;          // pad rows load a safe tile
        return wlane + (size_t)(tb + 3 * i + ob) * 2048;
      };
      auto body = [&](const short8 (&B)[4], int ii) {
        int i = ibeg + ii;
        ushort4 f0 = *(const ushort4*)&sF0[sf][i][q * 4];
        ushort4 f1 = *(const ushort4*)&sF0[sf][i][16 + q * 4];
        float4v C0 = {0.f, 0.f, 0.f, 0.f}, C1 = {0.f, 0.f, 0.f, 0.f};
        #pragma unroll
        for (int s = 0; s < 4; ++s) {
          C0 = __builtin_amdgcn_mfma_f32_16x16x32_bf16(Af[0][s], B[s], C0, 0, 0, 0);
          C1 = __builtin_amdgcn_mfma_f32_16x16x32_bf16(Af[1][s], B[s], C1, 0, 0, 0);
        }
        a0[0] += C0[0] * b2f(f0.x); a0[1] += C0[1] * b2f(f0.y);
        a0[2] += C0[2] * b2f(f0.z); a0[3] += C0[3] * b2f(f0.w);
        a1[0] += C1[0] * b2f(f1.x); a1[1] += C1[1] * b2f(f1.y);
        a1[2] += C1[2] * b2f(f1.z); a1[3] += C1[3] * b2f(f1.w);
      };
      issue4(Ba, addr(0));
      issue4(Bb, addr(1));
      #pragma unroll 1
      for (int ii = 0; ii < 28; ii += 2) {
        wait4(Ba); body(Ba, ii);     issue4(Ba, addr(ii + 2));
        wait4(Bb); body(Bb, ii + 1); issue4(Bb, addr(ii + 3));
      }
      wait4(Ba); body(Ba, 28);
      wait0(Bb); body(Bb, 29);
      const int col = obase + ob * 16 + l;
      #pragma unroll
      for (int r = 0; r < 4; ++r) {
        unsafeAtomicAdd(&sOut[q * 4 + r][col], a0[r]);
        unsafeAtomicAdd(&sOut[16 + q * 4 + r][col], a1[r]);
      }
    }
  } else {
    // ---------------- vector families (1o / 1e), i-half ----------------
    const int vf = (wv >> 1) - 2;
    const int ibeg = (wv & 1) ? 34 : 0;
    const int N = (wv & 1) ? 36 : 34;
    const int tb = vf ? 242 : 174;
    float r0[4][3] = {{0.f}}, r1[4][3] = {{0.f}};
    auto addr = [&](int ii) {
      int i = ibeg + ii; if (i >= 68) i = ibeg;
      return wlane + (size_t)(tb + i) * 2048;
    };
    auto body = [&](const short8 (&B)[4], int ii) {
      int i = ibeg + ii;
      ushort4 g0[3], g1[3];
      #pragma unroll
      for (int cc = 0; cc < 3; ++cc) {
        g0[cc] = *(const ushort4*)&sF1[vf][i][cc][q * 4];
        g1[cc] = *(const ushort4*)&sF1[vf][i][cc][16 + q * 4];
      }
      float4v C0 = {0.f, 0.f, 0.f, 0.f}, C1 = {0.f, 0.f, 0.f, 0.f};
      #pragma unroll
      for (int s = 0; s < 4; ++s) {
        C0 = __builtin_amdgcn_mfma_f32_16x16x32_bf16(Af[0][s], B[s], C0, 0, 0, 0);
        C1 = __builtin_amdgcn_mfma_f32_16x16x32_bf16(Af[1][s], B[s], C1, 0, 0, 0);
      }
      #pragma unroll
      for (int cc = 0; cc < 3; ++cc) {
        r0[0][cc] += C0[0] * b2f(g0[cc].x); r0[1][cc] += C0[1] * b2f(g0[cc].y);
        r0[2][cc] += C0[2] * b2f(g0[cc].z); r0[3][cc] += C0[3] * b2f(g0[cc].w);
        r1[0][cc] += C1[0] * b2f(g1[cc].x); r1[1][cc] += C1[1] * b2f(g1[cc].y);
        r1[2][cc] += C1[2] * b2f(g1[cc].z); r1[3][cc] += C1[3] * b2f(g1[cc].w);
      }
    };
    issue4(Ba, addr(0));
    issue4(Bb, addr(1));
    #pragma unroll 1
    for (int ii = 0; ii < N - 2; ii += 2) {
      wait4(Ba); body(Ba, ii);     issue4(Ba, addr(ii + 2));
      wait4(Bb); body(Bb, ii + 1); issue4(Bb, addr(ii + 3));
    }
    wait4(Ba); body(Ba, N - 2);
    wait0(Bb); body(Bb, N - 1);
    if (l < 10) {
      const int col = (vf ? 78 : 48) + 3 * l;
      #pragma unroll
      for (int r = 0; r < 4; ++r)
        #pragma unroll
        for (int cc = 0; cc < 3; ++cc) {
          unsafeAtomicAdd(&sOut[q * 4 + r][col + cc], r0[r][cc]);
          unsafeAtomicAdd(&sOut[16 + q * 4 + r][col + cc], r1[r][cc]);
        }
    }
  }
  __syncthreads();

  // ---- scatter to global ----
  const float n58 = 0.13130643285972254f, n68 = 0.12126781251816650f;
  for (int idx = tid; idx < EPW * IN_SZ; idx += 512) {
    int e = idx / IN_SZ, o = idx - e * IN_SZ;
    if (e0 + e < NE) {
      float nrm = (o < 48 || o >= 108) ? n58 : n68;
      unsafeAtomicAdd(&acc[(size_t)sSrc[e] * IN_SZ + o], sOut[e][o] * nrm);
    }
  }
}

// ---------------- Kernel 3: out = acc / max(cnt,1) + node_attr ----------------
__global__ __launch_bounds__(256) void finalize_kernel(
    const float* __restrict__ acc, const int* __restrict__ icnt,
    const float* __restrict__ node_attr, float* __restrict__ out)
{
  int idx = blockIdx.x * 256 + threadIdx.x;
  if (idx < NN * IN_SZ) {
    int n = idx / IN_SZ;
    out[idx] = acc[idx] / fmaxf((float)icnt[n], 1.f) + node_attr[idx];
  }
}

extern "C" void kernel_launch(void* const* d_in, const int* in_sizes, int n_in,
                              void* d_out, int out_size, void* d_ws, size_t ws_size,
                              hipStream_t stream)
{
  const float* node_attr  = (const float*)d_in[0];
  const int*   edge_index = (const int*)d_in[1];
  const float* edge_attr  = (const float*)d_in[2];
  const float* edge_sh    = (const float*)d_in[3];
  const float* W1 = (const float*)d_in[4];
  const float* b1 = (const float*)d_in[5];
  const float* W2 = (const float*)d_in[6];
  const float* b2 = (const float*)d_in[7];
  float* out = (float*)d_out;

  unsigned short* h_ext = (unsigned short*)d_ws;              // 50016 * 128 bf16
  unsigned short* W2PT  = h_ext + (size_t)50016 * KE;         // 484 tiles * 2048 shorts
  unsigned short* ea_bf = W2PT + (size_t)NTILE * 2048;        // 50000 * 96 bf16 (dead after mlp1)
  unsigned short* W1T   = ea_bf + (size_t)NE * KH;            // 96*96 bf16
  float* acc  = (float*)ea_bf;                                // ALIAS: reused after mlp1
  int*   icnt = (int*)(W1T + KH * KH + 64);                   // 10000 i32 (past W1T)

  cast_kernel<<<(NE * KH / 8 + KH * KH + 255) / 256, 256, 0, stream>>>(edge_attr, W1, ea_bf, W1T);
  w2pt_kernel<<<NTILE, 256, 0, stream>>>(W2, b2, W2PT);
  mlp1_kernel<<<NE / 16, 384, 0, stream>>>(ea_bf, W1T, b1, h_ext);
  hipMemsetAsync(acc, 0, (size_t)NN * IN_SZ * sizeof(float), stream);
  hipMemsetAsync(icnt, 0, (size_t)NN * sizeof(int), stream);
  hipMemsetAsync(h_ext + (size_t)50000 * KE, 0, (size_t)16 * KE * sizeof(unsigned short), stream);
  tp_kernel<<<(NE + EPW - 1) / EPW, 512, 0, stream>>>(h_ext, node_attr, edge_index,
                                                      edge_sh, W2PT, acc, icnt);
  finalize_kernel<<<(NN * IN_SZ + 255) / 256, 256, 0, stream>>>(acc, icnt, node_attr, out);
}